// Round 13
// baseline (2207.455 us; speedup 1.0000x reference)
//
#include <hip/hip_runtime.h>
#include <math.h>

// STCCapsNet forward. B=32, C=1, H=W=64, HP=WP=28, IN_CAPS=25088, OUT 32x2x16.
// Round 13: conv9x9 = r12 + explicit one-tap-ahead B prefetch (named register
// double sets, even/odd unrolled -- no runtime-indexed arrays). Phase/chunk
// boundary B prefetches issued before staging barriers. Rest identical to r12.

#define BSZ 32

typedef unsigned short u16;
using bf16x8 = __attribute__((ext_vector_type(8))) short;
using f32x4 = __attribute__((ext_vector_type(4))) float;

__device__ inline u16 f2bf(float f) {
  union { float f; unsigned u; } v; v.f = f;
  unsigned r = v.u + 0x7FFF + ((v.u >> 16) & 1);
  return (u16)(r >> 16);
}
__device__ inline float bf2f(u16 h) {
  union { unsigned u; float f; } v; v.u = ((unsigned)h) << 16;
  return v.f;
}

// ---------------------------------------------------------------- conv1d k=5 pad=2 + relu
__global__ __launch_bounds__(256) void conv1d_relu_k(
    const float* __restrict__ in, const float* __restrict__ w,
    const float* __restrict__ bias, float* __restrict__ out, int CI, int CO) {
  int idx = blockIdx.x * 256 + threadIdx.x;
  int total = BSZ * CO * 64;
  if (idx >= total) return;
  int x = idx & 63;
  int co = (idx >> 6) % CO;
  int b = idx / (64 * CO);
  const float* ip = in + (size_t)b * CI * 64;
  const float* wp = w + (size_t)co * CI * 5;
  float acc = bias[co];
  for (int ci = 0; ci < CI; ++ci) {
    const float* ir = ip + ci * 64;
    const float* wr_ = wp + ci * 5;
#pragma unroll
    for (int k = 0; k < 5; ++k) {
      int xx = x + k - 2;
      if (xx >= 0 && xx < 64) acc += ir[xx] * wr_[k];
    }
  }
  out[idx] = fmaxf(acc, 0.f);
}

// ---------------------------------------------------------------- conv2d 3x3 pad=1 + relu (scalar; s1 only)
template <int CI, int CIC>
__global__ __launch_bounds__(256) void conv3x3_relu_k(
    const float* __restrict__ in, const float* __restrict__ w,
    const float* __restrict__ bias, float* __restrict__ out, int CO) {
  __shared__ float in_t[CIC][18][20];
  __shared__ float w_t[CIC][16][12];
  int t = threadIdx.x;
  int co_l = t & 15;
  int g = t >> 4;
  int gy = g >> 2, gx = g & 3;
  int y0 = (blockIdx.x >> 2) * 16, x0 = (blockIdx.x & 3) * 16;
  int co = blockIdx.y * 16 + co_l;
  int b = blockIdx.z;
  float acc[16];
#pragma unroll
  for (int i = 0; i < 16; ++i) acc[i] = 0.f;

  for (int cib = 0; cib < CI / CIC; ++cib) {
    int ci0 = cib * CIC;
    for (int s = t; s < CIC * 324; s += 256) {
      int ci = s / 324;
      int r = s - ci * 324;
      int iy = r / 18, ix = r - iy * 18;
      int gyy = y0 + iy - 1, gxx = x0 + ix - 1;
      float v = 0.f;
      if (gyy >= 0 && gyy < 64 && gxx >= 0 && gxx < 64)
        v = in[((size_t)b * CI + ci0 + ci) * 4096 + gyy * 64 + gxx];
      in_t[ci][iy][ix] = v;
    }
    for (int s = t; s < CIC * 144; s += 256) {
      int ci = s / 144;
      int r = s - ci * 144;
      int cw = r / 9, k = r - cw * 9;
      w_t[ci][cw][k] = w[((size_t)(blockIdx.y * 16 + cw) * CI + ci0 + ci) * 9 + k];
    }
    __syncthreads();
    for (int ci = 0; ci < CIC; ++ci) {
      float wv[9];
#pragma unroll
      for (int k = 0; k < 9; ++k) wv[k] = w_t[ci][co_l][k];
      float pin[36];
#pragma unroll
      for (int r6 = 0; r6 < 6; ++r6)
#pragma unroll
        for (int c6 = 0; c6 < 6; ++c6)
          pin[r6 * 6 + c6] = in_t[ci][4 * gy + r6][4 * gx + c6];
#pragma unroll
      for (int py = 0; py < 4; ++py)
#pragma unroll
        for (int px = 0; px < 4; ++px) {
          float s_ = acc[py * 4 + px];
#pragma unroll
          for (int ky = 0; ky < 3; ++ky)
#pragma unroll
            for (int kx = 0; kx < 3; ++kx)
              s_ += pin[(py + ky) * 6 + (px + kx)] * wv[ky * 3 + kx];
          acc[py * 4 + px] = s_;
        }
    }
    __syncthreads();
  }
  float bv = bias[co];
#pragma unroll
  for (int py = 0; py < 4; ++py)
#pragma unroll
    for (int px = 0; px < 4; ++px)
      out[((size_t)b * CO + co) * 4096 + (size_t)(y0 + 4 * gy + py) * 64 +
          (x0 + 4 * gx + px)] = fmaxf(acc[py * 4 + px] + bv, 0.f);
}

// ---------------------------------------------------------------- w_f transpose (256,260)->(260,256)
__global__ __launch_bounds__(256) void transpose_wf_k(const float* __restrict__ wf,
                                                      float* __restrict__ wfT) {
  int idx = blockIdx.x * 256 + threadIdx.x;
  if (idx >= 256 * 260) return;
  int co = idx / 260, c = idx - co * 260;
  wfT[c * 256 + co] = wf[idx];
}

// ---------------------------------------------------------------- w_p -> WT_hi/WT_lo [g*81+tap][co][ci%32]
__global__ __launch_bounds__(256) void transpose_wp_k(const float* __restrict__ wp,
                                                      u16* __restrict__ wth,
                                                      u16* __restrict__ wtl) {
  int s = blockIdx.x;  // 0..647 = g*81 + tap
  int g = s / 81, t = s - g * 81;
  int co = threadIdx.x;
  u16 th[32], tl[32];
#pragma unroll
  for (int c = 0; c < 32; ++c) {
    float f = wp[((size_t)co * 256 + g * 32 + c) * 81 + t];
    u16 h = f2bf(f);
    th[c] = h;
    tl[c] = f2bf(f - bf2f(h));
  }
  ushort4* dh = (ushort4*)(wth + ((size_t)s * 256 + co) * 32);
  ushort4* dl = (ushort4*)(wtl + ((size_t)s * 256 + co) * 32);
#pragma unroll
  for (int q = 0; q < 8; ++q) {
    dh[q] = make_ushort4(th[4 * q], th[4 * q + 1], th[4 * q + 2], th[4 * q + 3]);
    dl[q] = make_ushort4(tl[4 * q], tl[4 * q + 1], tl[4 * q + 2], tl[4 * q + 3]);
  }
}

// ---------------------------------------------------------------- w3 (CO,CI,3,3) -> [g*9+tap][co][32] hi/lo
template <int CO, int NCHUNK>
__global__ __launch_bounds__(256) void transpose_w3_k(const float* __restrict__ w,
                                                      u16* __restrict__ wh,
                                                      u16* __restrict__ wl) {
  int tab = blockIdx.x;  // NCHUNK*9
  int g = tab / 9, tap = tab - g * 9;
  int co = threadIdx.x;
  if (co >= CO) return;
  constexpr int CI = NCHUNK * 32;
  u16 th[32], tl[32];
#pragma unroll
  for (int c = 0; c < 32; ++c) {
    float f = w[((size_t)co * CI + g * 32 + c) * 9 + tap];
    u16 h = f2bf(f);
    th[c] = h;
    tl[c] = f2bf(f - bf2f(h));
  }
  ushort4* dh = (ushort4*)(wh + ((size_t)tab * CO + co) * 32);
  ushort4* dl = (ushort4*)(wl + ((size_t)tab * CO + co) * 32);
#pragma unroll
  for (int q = 0; q < 8; ++q) {
    dh[q] = make_ushort4(th[4 * q], th[4 * q + 1], th[4 * q + 2], th[4 * q + 3]);
    dl[q] = make_ushort4(tl[4 * q], tl[4 * q + 1], tl[4 * q + 2], tl[4 * q + 3]);
  }
}

// ---------------------------------------------------------------- conv3x3 pad=1 s=1 via MFMA hi/lo 3-pass + relu
// (round-5 proven version)
template <int WM, int WN, int NCHUNK, int CO>
__global__ __launch_bounds__(512) void conv3x3_mfma_k(const float* __restrict__ in,
                                                      const u16* __restrict__ Wh,
                                                      const u16* __restrict__ Wl,
                                                      const float* __restrict__ bias,
                                                      float* __restrict__ out) {
  constexpr int CI = NCHUNK * 32;
  constexpr int ROWS = WM + 2;
  constexpr int KSTEPS = NCHUNK * 9;
  constexpr int NSTEPS = 3 * KSTEPS;
  constexpr int NV4 = CO / 128;
  __shared__ __align__(16) char lds_a[ROWS * 66 * 80];
  __shared__ __align__(16) char lds_b[2][CO * 80];
  const int tid = threadIdx.x;
  const int b = blockIdx.y;
  const int y0 = blockIdx.x * WM;
  const int w = tid >> 6, l = tid & 63;
  const int wm = w / WN, wn = w % WN;
  const int kb = l >> 4, il = l & 15;

  int abase[4];
#pragma unroll
  for (int mb = 0; mb < 4; ++mb) {
    int lp = (wm * 4 + mb) * 16 + il;
    int ly = lp >> 6, lx = lp & 63;
    abase[mb] = (ly * 66 + lx) * 80 + kb * 16;
  }
  int bbase[4];
#pragma unroll
  for (int nbi = 0; nbi < 4; ++nbi)
    bbase[nbi] = (wn * 64 + nbi * 16 + il) * 80 + kb * 16;

  f32x4 acc[4][4];
#pragma unroll
  for (int mb = 0; mb < 4; ++mb)
#pragma unroll
    for (int nbi = 0; nbi < 4; ++nbi) {
      f32x4 z = {0.f, 0.f, 0.f, 0.f};
      acc[mb][nbi] = z;
    }

  const float* Fb = in + (size_t)b * CI * 4096;
  float4 nb[NV4];

  auto stageA = [&](int g, int plane) {
    const float* src = Fb + (size_t)g * 32 * 4096;
    for (int s = tid; s < ROWS * 66 * 8; s += 512) {
      int ciq = s & 7;
      int rest = s >> 3;
      int r = rest / 66, x = rest - r * 66;
      int row = y0 - 1 + r, col = x - 1;
      float a0 = 0.f, a1 = 0.f, a2 = 0.f, a3 = 0.f;
      if (row >= 0 && row < 64 && col >= 0 && col < 64) {
        const float* p = src + (size_t)(ciq * 4) * 4096 + row * 64 + col;
        a0 = p[0];
        a1 = p[4096];
        a2 = p[8192];
        a3 = p[12288];
      }
      u16 e0, e1, e2, e3;
      if (plane == 0) {
        e0 = f2bf(a0); e1 = f2bf(a1); e2 = f2bf(a2); e3 = f2bf(a3);
      } else {
        u16 h0 = f2bf(a0), h1 = f2bf(a1), h2 = f2bf(a2), h3 = f2bf(a3);
        e0 = f2bf(a0 - bf2f(h0)); e1 = f2bf(a1 - bf2f(h1));
        e2 = f2bf(a2 - bf2f(h2)); e3 = f2bf(a3 - bf2f(h3));
      }
      *(ushort4*)(lds_a + (r * 66 + x) * 80 + ciq * 8) = make_ushort4(e0, e1, e2, e3);
    }
  };
  auto prefB = [&](int stepn) {
    int within = stepn % KSTEPS;
    const u16* W = (stepn >= 2 * KSTEPS) ? Wl : Wh;
    const char* p = (const char*)W + (size_t)within * CO * 64;
#pragma unroll
    for (int q = 0; q < NV4; ++q) nb[q] = *(const float4*)(p + (tid + q * 512) * 16);
  };
  auto writeB = [&](int buf) {
#pragma unroll
    for (int q = 0; q < NV4; ++q) {
      int u = tid + q * 512;
      *(float4*)(&lds_b[buf][(u >> 2) * 80 + (u & 3) * 16]) = nb[q];
    }
  };

  stageA(0, 0);
  prefB(0);
  writeB(0);

  int step = 0;
  for (int pass = 0; pass < 3; ++pass) {
    for (int g = 0; g < NCHUNK; ++g) {
      for (int tap = 0; tap < 9; ++tap, ++step) {
        __syncthreads();
        if (step + 1 < NSTEPS) prefB(step + 1);
        int ky = tap / 3, kx = tap - ky * 3;
        int koff = (ky * 66 + kx) * 80;
        int bsel = step & 1;
        bf16x8 av[4], bv[4];
#pragma unroll
        for (int mb = 0; mb < 4; ++mb)
          av[mb] = *(const bf16x8*)(lds_a + abase[mb] + koff);
#pragma unroll
        for (int nbi = 0; nbi < 4; ++nbi)
          bv[nbi] = *(const bf16x8*)(&lds_b[bsel][bbase[nbi]]);
#pragma unroll
        for (int mb = 0; mb < 4; ++mb)
#pragma unroll
          for (int nbi = 0; nbi < 4; ++nbi)
            acc[mb][nbi] = __builtin_amdgcn_mfma_f32_16x16x32_bf16(
                av[mb], bv[nbi], acc[mb][nbi], 0, 0, 0);
        if (step + 1 < NSTEPS) writeB((step + 1) & 1);
        if (tap == 8 && step + 1 < NSTEPS) {
          __syncthreads();
          int ns = step + 1;
          int npass = ns / KSTEPS;
          int ng = (ns % KSTEPS) / 9;
          stageA(ng, (npass == 1) ? 1 : 0);
        }
      }
    }
  }

  const int p0 = y0 * 64;
#pragma unroll
  for (int mb = 0; mb < 4; ++mb) {
    int pixb = p0 + (wm * 4 + mb) * 16 + kb * 4;
#pragma unroll
    for (int nbi = 0; nbi < 4; ++nbi) {
      int co = wn * 64 + nbi * 16 + il;
      float bv_ = bias[co];
      f32x4 a = acc[mb][nbi];
      float4 o = make_float4(fmaxf(a[0] + bv_, 0.f), fmaxf(a[1] + bv_, 0.f),
                             fmaxf(a[2] + bv_, 0.f), fmaxf(a[3] + bv_, 0.f));
      *(float4*)(out + (size_t)(b * CO + co) * 4096 + pixb) = o;
    }
  }
}

// ---------------------------------------------------------------- 1x1 fusion conv, fp32 IN-PLACE
__global__ __launch_bounds__(256) void fuse1x1_k(const float* __restrict__ t3,
                                                 const float* __restrict__ wfT,
                                                 const float* __restrict__ bf,
                                                 float* __restrict__ a) {
  __shared__ float in_t[260][32];
  int t = threadIdx.x;
  int b = blockIdx.x >> 7;
  int p0 = (blockIdx.x & 127) * 32;
  for (int s = t; s < 260 * 32; s += 256) {
    int c = s >> 5, pp = s & 31;
    float v;
    if (c < 4)
      v = t3[(size_t)b * 16384 + c * 4096 + p0 + pp];
    else
      v = a[((size_t)b * 256 + (c - 4)) * 4096 + p0 + pp];
    in_t[c][pp] = v;
  }
  __syncthreads();
  int co = t;
  float acc[32];
#pragma unroll
  for (int pp = 0; pp < 32; ++pp) acc[pp] = 0.f;
  for (int c = 0; c < 260; ++c) {
    float wv = wfT[c * 256 + co];
#pragma unroll
    for (int pp = 0; pp < 32; ++pp) acc[pp] += wv * in_t[c][pp];
  }
  float bv = bf[co];
#pragma unroll
  for (int pp = 0; pp < 32; ++pp)
    a[((size_t)b * 256 + co) * 4096 + p0 + pp] = acc[pp] + bv;
}

// ---------------------------------------------------------------- 9x9 s2 conv, MFMA hi/lo
// A in LDS (parity-split, clean); B global->regs with one-tap-ahead prefetch
// (named double register sets, even/odd unrolled). No lds_b, no per-tap barrier.
__global__ __launch_bounds__(512) void conv9x9_mfma_k(const float* __restrict__ fused,
                                                      const u16* __restrict__ WTh,
                                                      const u16* __restrict__ WTl,
                                                      const float* __restrict__ bias,
                                                      float* __restrict__ praw) {
  constexpr int APLANE = 19 * 32 * 80;  // 48640 B per parity plane
  __shared__ __align__(16) char lds_a[2 * APLANE];   // 97280
  const int tid = threadIdx.x;
  const int b = blockIdx.y, tile = blockIdx.x;
  const int p0 = tile * 128;
  const int oy0 = p0 / 28;
  const int w = tid >> 6, l = tid & 63;
  const int wm = w >> 2, wn = w & 3;
  const int kb = l >> 4, il = l & 15;

  int abase[4];
#pragma unroll
  for (int mb = 0; mb < 4; ++mb) {
    int p = p0 + (wm * 4 + mb) * 16 + il;
    int oy = p / 28, ox = p - oy * 28;
    abase[mb] = (2 * (oy - oy0)) * 2560 + ox * 80 + kb * 16;
  }
  int boff[4];  // byte offset within one tap's 16384B weight block
#pragma unroll
  for (int nbi = 0; nbi < 4; ++nbi)
    boff[nbi] = (wn * 64 + nbi * 16 + il) * 64 + kb * 16;

  f32x4 acc[4][4];
#pragma unroll
  for (int mb = 0; mb < 4; ++mb)
#pragma unroll
    for (int nbi = 0; nbi < 4; ++nbi) {
      f32x4 z = {0.f, 0.f, 0.f, 0.f};
      acc[mb][nbi] = z;
    }

  const float* Fb = fused + (size_t)b * 256 * 4096;
  const char* WhB = (const char*)WTh;
  const char* WlB = (const char*)WTl;

  auto stageA = [&](int g, int plane) {
    const float* src = Fb + (size_t)g * 32 * 4096;
    for (int s = tid; s < 19 * 63 * 8; s += 512) {
      int ciq = s / 1197;
      int rem = s - ciq * 1197;
      int r = rem / 63, t63 = rem - r * 63;
      int x2 = (t63 < 32) ? 2 * t63 : 2 * (t63 - 32) + 1;  // parity-major lane map
      int iy = 2 * oy0 + r;
      float a0 = 0.f, a1 = 0.f, a2 = 0.f, a3 = 0.f;
      if (iy < 64) {
        const float* pp0 = src + (size_t)(ciq * 4) * 4096 + iy * 64 + x2;
        a0 = pp0[0];
        a1 = pp0[4096];
        a2 = pp0[8192];
        a3 = pp0[12288];
      }
      u16 e0, e1, e2, e3;
      if (plane == 0) {
        e0 = f2bf(a0); e1 = f2bf(a1); e2 = f2bf(a2); e3 = f2bf(a3);
      } else {
        u16 h0 = f2bf(a0), h1 = f2bf(a1), h2 = f2bf(a2), h3 = f2bf(a3);
        e0 = f2bf(a0 - bf2f(h0)); e1 = f2bf(a1 - bf2f(h1));
        e2 = f2bf(a2 - bf2f(h2)); e3 = f2bf(a3 - bf2f(h3));
      }
      int off = (x2 & 1) * APLANE + (r * 32 + (x2 >> 1)) * 80 + ciq * 8;
      *(ushort4*)(lds_a + off) = make_ushort4(e0, e1, e2, e3);
    }
  };

  auto loadB2 = [&](int gt, bf16x8 (&bh)[4], bf16x8 (&bl)[4]) {
    const char* pb = WhB + (size_t)gt * 16384;
    const char* pl = WlB + (size_t)gt * 16384;
#pragma unroll
    for (int nbi = 0; nbi < 4; ++nbi) {
      bh[nbi] = *(const bf16x8*)(pb + boff[nbi]);
      bl[nbi] = *(const bf16x8*)(pl + boff[nbi]);
    }
  };
  auto loadB1 = [&](int gt, bf16x8 (&bh)[4]) {
    const char* pb = WhB + (size_t)gt * 16384;
#pragma unroll
    for (int nbi = 0; nbi < 4; ++nbi)
      bh[nbi] = *(const bf16x8*)(pb + boff[nbi]);
  };
  auto mfmaDual = [&](int t, const bf16x8 (&bh)[4], const bf16x8 (&bl)[4]) {
    int ky = t / 9, kx = t - ky * 9;
    int toff = (kx & 1) * APLANE + ky * 2560 + (kx >> 1) * 80;
    bf16x8 av[4];
#pragma unroll
    for (int mb = 0; mb < 4; ++mb)
      av[mb] = *(const bf16x8*)(lds_a + abase[mb] + toff);
#pragma unroll
    for (int mb = 0; mb < 4; ++mb)
#pragma unroll
      for (int nbi = 0; nbi < 4; ++nbi) {
        acc[mb][nbi] = __builtin_amdgcn_mfma_f32_16x16x32_bf16(
            av[mb], bh[nbi], acc[mb][nbi], 0, 0, 0);
        acc[mb][nbi] = __builtin_amdgcn_mfma_f32_16x16x32_bf16(
            av[mb], bl[nbi], acc[mb][nbi], 0, 0, 0);
      }
  };
  auto mfmaOne = [&](int t, const bf16x8 (&bh)[4]) {
    int ky = t / 9, kx = t - ky * 9;
    int toff = (kx & 1) * APLANE + ky * 2560 + (kx >> 1) * 80;
    bf16x8 av[4];
#pragma unroll
    for (int mb = 0; mb < 4; ++mb)
      av[mb] = *(const bf16x8*)(lds_a + abase[mb] + toff);
#pragma unroll
    for (int mb = 0; mb < 4; ++mb)
#pragma unroll
      for (int nbi = 0; nbi < 4; ++nbi)
        acc[mb][nbi] = __builtin_amdgcn_mfma_f32_16x16x32_bf16(
            av[mb], bh[nbi], acc[mb][nbi], 0, 0, 0);
  };

  bf16x8 h0[4], l0[4], h1[4], l1[4];

  loadB2(0, h0, l0);  // prologue: g=0 phase0 tap0

  for (int g = 0; g < 8; ++g) {
    const int base = g * 81;
    // ---- phase 0: Ah x Bh + Ah x Bl ----
    __syncthreads();
    stageA(g, 0);
    __syncthreads();
    for (int tt = 0; tt < 81; tt += 2) {
      if (tt + 1 < 81) loadB2(base + tt + 1, h1, l1);
      mfmaDual(tt, h0, l0);
      if (tt + 1 < 81) {
        if (tt + 2 < 81) loadB2(base + tt + 2, h0, l0);
        mfmaDual(tt + 1, h1, l1);
      }
    }
    // prefetch phase1 tap0 before the staging barriers (latency hidden by stageA)
    loadB1(base, h0);
    // ---- phase 1: Al x Bh ----
    __syncthreads();
    stageA(g, 1);
    __syncthreads();
    for (int tt = 0; tt < 81; tt += 2) {
      if (tt + 1 < 81) loadB1(base + tt + 1, h1);
      mfmaOne(tt, h0);
      if (tt + 1 < 81) {
        if (tt + 2 < 81) loadB1(base + tt + 2, h0);
        mfmaOne(tt + 1, h1);
      }
    }
    // prefetch next chunk's phase0 tap0
    if (g < 7) loadB2(base + 81, h0, l0);
  }

#pragma unroll
  for (int mb = 0; mb < 4; ++mb) {
    int pixb = p0 + (wm * 4 + mb) * 16 + kb * 4;
    if (pixb < 784) {
#pragma unroll
      for (int nbi = 0; nbi < 4; ++nbi) {
        int co = wn * 64 + nbi * 16 + il;
        float bv_ = bias[co];
        f32x4 a = acc[mb][nbi];
        float4 o = make_float4(a[0] + bv_, a[1] + bv_, a[2] + bv_, a[3] + bv_);
        *(float4*)(praw + (size_t)(b * 256 + co) * 784 + pixb) = o;
      }
    }
  }
}

// ---------------------------------------------------------------- capsule squash: p(B,256,784) -> u(B,25088,8)
__global__ __launch_bounds__(256) void squash_caps_k(const float* __restrict__ p,
                                                     float* __restrict__ u) {
  int idx = blockIdx.x * 256 + threadIdx.x;
  if (idx >= BSZ * 25088) return;
  int b = idx / 25088;
  int cap = idx - b * 25088;
  int prim = cap / 784, pix = cap - prim * 784;
  const float* pp = p + ((size_t)b * 256 + prim * 8) * 784 + pix;
  float x[8];
  float sn = 0.f;
#pragma unroll
  for (int d = 0; d < 8; ++d) {
    x[d] = pp[(size_t)d * 784];
    sn += x[d] * x[d];
  }
  float scale = sn / ((1.f + sn) * sqrtf(sn + 1e-8f));
  float4 r0 = {x[0] * scale, x[1] * scale, x[2] * scale, x[3] * scale};
  float4 r1 = {x[4] * scale, x[5] * scale, x[6] * scale, x[7] * scale};
  float4* dst = (float4*)(u + (size_t)idx * 8);
  dst[0] = r0;
  dst[1] = r1;
}

// ---------------------------------------------------------------- u_hat = einsum('iodk,bik->biod')
__global__ __launch_bounds__(256) void uhat_k(const float* __restrict__ u,
                                              const float* __restrict__ w_r,
                                              float* __restrict__ u_hat) {
  int i = blockIdx.x * 256 + threadIdx.x;  // 25088
  int b = blockIdx.y;
  const float4* up = (const float4*)(u + ((size_t)b * 25088 + i) * 8);
  float4 ua = up[0], ub = up[1];
  const float4* wr = (const float4*)(w_r + (size_t)i * 256);
  float res[32];
#pragma unroll
  for (int od = 0; od < 32; ++od) {
    float4 wa = wr[od * 2], wb = wr[od * 2 + 1];
    res[od] = wa.x * ua.x + wa.y * ua.y + wa.z * ua.z + wa.w * ua.w +
              wb.x * ub.x + wb.y * ub.y + wb.z * ub.z + wb.w * ub.w;
  }
  float4* dst = (float4*)(u_hat + ((size_t)b * 25088 + i) * 32);
#pragma unroll
  for (int q = 0; q < 8; ++q)
    dst[q] = make_float4(res[4 * q], res[4 * q + 1], res[4 * q + 2], res[4 * q + 3]);
}

// ---------------------------------------------------------------- routing: partial s_j per (b,seg)
__global__ __launch_bounds__(256) void route_sj_k(const float* __restrict__ u_hat,
                                                  const float* __restrict__ b_ij,
                                                  float* __restrict__ sj_part, int iter) {
  int b = blockIdx.x;
  int seg = blockIdx.y;
  int t = threadIdx.x;
  float acc[32];
#pragma unroll
  for (int j = 0; j < 32; ++j) acc[j] = 0.f;
  int i0 = seg * 3136;
  for (int i = i0 + t; i < i0 + 3136; i += 256) {
    float c0 = 0.5f, c1 = 0.5f;
    if (iter > 0) {
      float b0 = b_ij[((size_t)b * 25088 + i) * 2 + 0];
      float b1 = b_ij[((size_t)b * 25088 + i) * 2 + 1];
      float m = fmaxf(b0, b1);
      float e0 = expf(b0 - m), e1 = expf(b1 - m);
      float inv = 1.f / (e0 + e1);
      c0 = e0 * inv;
      c1 = e1 * inv;
    }
    const float4* uh = (const float4*)(u_hat + ((size_t)b * 25088 + i) * 32);
#pragma unroll
    for (int q = 0; q < 4; ++q) {
      float4 va = uh[q];
      acc[4 * q + 0] += c0 * va.x;
      acc[4 * q + 1] += c0 * va.y;
      acc[4 * q + 2] += c0 * va.z;
      acc[4 * q + 3] += c0 * va.w;
      float4 vb = uh[4 + q];
      acc[16 + 4 * q + 0] += c1 * vb.x;
      acc[16 + 4 * q + 1] += c1 * vb.y;
      acc[16 + 4 * q + 2] += c1 * vb.z;
      acc[16 + 4 * q + 3] += c1 * vb.w;
    }
  }
#pragma unroll
  for (int j = 0; j < 32; ++j) {
    acc[j] += __shfl_down(acc[j], 32);
    acc[j] += __shfl_down(acc[j], 16);
    acc[j] += __shfl_down(acc[j], 8);
    acc[j] += __shfl_down(acc[j], 4);
    acc[j] += __shfl_down(acc[j], 2);
    acc[j] += __shfl_down(acc[j], 1);
  }
  __shared__ float red[4][32];
  int wave = t >> 6, lane = t & 63;
  if (lane == 0) {
#pragma unroll
    for (int j = 0; j < 32; ++j) red[wave][j] = acc[j];
  }
  __syncthreads();
  if (t < 32) {
    float s = red[0][t] + red[1][t] + red[2][t] + red[3][t];
    sj_part[((size_t)b * 8 + seg) * 32 + t] = s;
  }
}

// ---------------------------------------------------------------- routing: finalize v
__global__ __launch_bounds__(256) void route_fin_k(const float* __restrict__ sj_part,
                                                   float* __restrict__ v,
                                                   float* __restrict__ out, int final_it) {
  int idx = blockIdx.x * 256 + threadIdx.x;
  if (idx >= BSZ * 32) return;
  int b = idx >> 5, j = idx & 31;
  float s = 0.f;
#pragma unroll
  for (int seg = 0; seg < 8; ++seg) s += sj_part[((size_t)b * 8 + seg) * 32 + j];
  float sn = s * s;
  float vv = sn * s / ((1.f + sn) * sqrtf(sn + 1e-8f));
  v[idx] = vv;
  if (final_it) out[idx] = fabsf(vv);
}

// ---------------------------------------------------------------- routing: b_ij update
__global__ __launch_bounds__(256) void route_upd_k(const float* __restrict__ u_hat,
                                                   const float* __restrict__ v,
                                                   float* __restrict__ b_ij, int first) {
  int i = blockIdx.x * 256 + threadIdx.x;  // 25088
  int b = blockIdx.y;
  const float4* uh = (const float4*)(u_hat + ((size_t)b * 25088 + i) * 32);
  const float4* vp = (const float4*)(v + b * 32);
  float e0 = 0.f, e1 = 0.f;
#pragma unroll
  for (int q = 0; q < 4; ++q) {
    float4 a = uh[q], wv = vp[q];
    e0 += a.x * wv.x + a.y * wv.y + a.z * wv.z + a.w * wv.w;
    float4 a2 = uh[4 + q], w2 = vp[4 + q];
    e1 += a2.x * w2.x + a2.y * w2.y + a2.z * w2.z + a2.w * w2.w;
  }
  size_t o = ((size_t)b * 25088 + i) * 2;
  if (first) {
    b_ij[o + 0] = e0;
    b_ij[o + 1] = e1;
  } else {
    b_ij[o + 0] += e0;
    b_ij[o + 1] += e1;
  }
}

// ================================================================ launch
extern "C" void kernel_launch(void* const* d_in, const int* in_sizes, int n_in,
                              void* d_out, int out_size, void* d_ws, size_t ws_size,
                              hipStream_t stream) {
  (void)in_sizes; (void)n_in; (void)out_size;
  const float* x    = (const float*)d_in[0];
  const float* w_t1 = (const float*)d_in[1];
  const float* b_t1 = (const float*)d_in[2];
  const float* w_t2 = (const float*)d_in[3];
  const float* b_t2 = (const float*)d_in[4];
  const float* w_t3 = (const float*)d_in[5];
  const float* b_t3 = (const float*)d_in[6];
  const float* w_s1 = (const float*)d_in[7];
  const float* b_s1 = (const float*)d_in[8];
  const float* w_s2 = (const float*)d_in[9];
  const float* b_s2 = (const float*)d_in[10];
  const float* w_s3 = (const float*)d_in[11];
  const float* b_s3 = (const float*)d_in[12];
  const float* w_f  = (const float*)d_in[13];
  const float* b_f  = (const float*)d_in[14];
  const float* w_p  = (const float*)d_in[15];
  const float* b_p  = (const float*)d_in[16];
  const float* w_r  = (const float*)d_in[17];
  float* out = (float*)d_out;

  char* ws = (char*)d_ws;
  if (ws_size < 238854144ull) return;
  // region 0: fused / uhat
  float* fused = (float*)(ws + 0);
  float* uhat  = (float*)(ws + 0);
  // region 1 (134,217,728): s2q -> praw/u/b_ij
  float* s2q   = (float*)(ws + 134217728);
  float* praw  = (float*)(ws + 134217728);
  float* u     = (float*)(ws + 159907840);
  float* b_ij  = (float*)(ws + 185597952);
  // region 2 (201,326,592): s1 -> t1/t2/t3/wTh/wTl
  float* s1    = (float*)(ws + 201326592);
  float* t1    = (float*)(ws + 201326592);
  float* t2    = (float*)(ws + 201850880);
  float* t3    = (float*)(ws + 202899456);
  u16*   wTh   = (u16*)  (ws + 204996608);
  u16*   wTl   = (u16*)  (ws + 215613440);
  // tail (234,881,024): persistent small tables
  u16*   w3a_h = (u16*)  (ws + 234881024);
  u16*   w3a_l = (u16*)  (ws + 235028480);
  u16*   w3b_h = (u16*)  (ws + 235175936);
  u16*   w3b_l = (u16*)  (ws + 235765760);
  float* wfT   = (float*)(ws + 236355584);
  float* sjp   = (float*)(ws + 236621824);
  float* vbuf  = (float*)(ws + 236654592);

  // small weight tables (tail region -- never clobbered)
  transpose_w3_k<128, 2><<<18, 256, 0, stream>>>(w_s2, w3a_h, w3a_l);
  transpose_w3_k<256, 4><<<36, 256, 0, stream>>>(w_s3, w3b_h, w3b_l);
  transpose_wf_k<<<261, 256, 0, stream>>>(w_f, wfT);

  // spectral: s1 scalar conv, then s2 MFMA conv (consumes s1)
  conv3x3_relu_k<1, 1><<<dim3(16, 4, BSZ), 256, 0, stream>>>(x, w_s1, b_s1, s1, 64);
  conv3x3_mfma_k<4, 2, 2, 128><<<dim3(16, BSZ), 512, 0, stream>>>(s1, w3a_h, w3a_l, b_s2, s2q);

  // s1 now dead: temporal branch + 9x9 weight tables move into its region
  conv1d_relu_k<<<512, 256, 0, stream>>>(x, w_t1, b_t1, t1, 64, 64);
  conv1d_relu_k<<<1024, 256, 0, stream>>>(t1, w_t2, b_t2, t2, 64, 128);
  conv1d_relu_k<<<2048, 256, 0, stream>>>(t2, w_t3, b_t3, t3, 128, 256);
  transpose_wp_k<<<648, 256, 0, stream>>>(w_p, wTh, wTl);

  // s3 MFMA conv -> fused
  conv3x3_mfma_k<2, 4, 4, 256><<<dim3(32, BSZ), 512, 0, stream>>>(s2q, w3b_h, w3b_l, b_s3, fused);

  // fusion fp32 in-place
  fuse1x1_k<<<4096, 256, 0, stream>>>(t3, wfT, b_f, fused);

  // primary capsules via MFMA hi/lo (praw over dead s2q)
  conv9x9_mfma_k<<<dim3(7, BSZ), 512, 0, stream>>>(fused, wTh, wTl, b_p, praw);
  squash_caps_k<<<3136, 256, 0, stream>>>(praw, u);

  // u_hat (overwrites fused region)
  uhat_k<<<dim3(98, BSZ), 256, 0, stream>>>(u, w_r, uhat);

  // dynamic routing, 3 iterations
  route_sj_k<<<dim3(BSZ, 8), 256, 0, stream>>>(uhat, b_ij, sjp, 0);
  route_fin_k<<<4, 256, 0, stream>>>(sjp, vbuf, out, 0);
  route_upd_k<<<dim3(98, BSZ), 256, 0, stream>>>(uhat, vbuf, b_ij, 1);

  route_sj_k<<<dim3(BSZ, 8), 256, 0, stream>>>(uhat, b_ij, sjp, 1);
  route_fin_k<<<4, 256, 0, stream>>>(sjp, vbuf, out, 0);
  route_upd_k<<<dim3(98, BSZ), 256, 0, stream>>>(uhat, vbuf, b_ij, 0);

  route_sj_k<<<dim3(BSZ, 8), 256, 0, stream>>>(uhat, b_ij, sjp, 2);
  route_fin_k<<<4, 256, 0, stream>>>(sjp, vbuf, out, 1);
}

// Round 14
// 1847.276 us; speedup vs baseline: 1.1950x; 1.1950x over previous
//
#include <hip/hip_runtime.h>
#include <math.h>

// STCCapsNet forward. B=32, C=1, H=W=64, HP=WP=28, IN_CAPS=25088, OUT 32x2x16.
// Round 14: conv9x9 -> 2-pass mixed precision: A single fp16 (err 2^-11),
// B fp16 hi/lo (exact to 2^-22). Per chunk: stage A once -> 81 taps x {A*Bh + A*Bl}.
// MFMA/staging/barriers all reduced; layout identical (parity-split, 97KB LDS).
// conv3x3s remain exact bf16 3-pass.

#define BSZ 32

typedef unsigned short u16;
using bf16x8 = __attribute__((ext_vector_type(8))) short;
using f16x8 = __attribute__((ext_vector_type(8))) _Float16;
using f32x4 = __attribute__((ext_vector_type(4))) float;

__device__ inline u16 f2bf(float f) {
  union { float f; unsigned u; } v; v.f = f;
  unsigned r = v.u + 0x7FFF + ((v.u >> 16) & 1);
  return (u16)(r >> 16);
}
__device__ inline float bf2f(u16 h) {
  union { unsigned u; float f; } v; v.u = ((unsigned)h) << 16;
  return v.f;
}
__device__ inline u16 f2h(float f) {
  union { _Float16 h; u16 u; } v; v.h = (_Float16)f;
  return v.u;
}
__device__ inline float h2f(u16 b) {
  union { u16 u; _Float16 h; } v; v.u = b;
  return (float)v.h;
}

// ---------------------------------------------------------------- conv1d k=5 pad=2 + relu
__global__ __launch_bounds__(256) void conv1d_relu_k(
    const float* __restrict__ in, const float* __restrict__ w,
    const float* __restrict__ bias, float* __restrict__ out, int CI, int CO) {
  int idx = blockIdx.x * 256 + threadIdx.x;
  int total = BSZ * CO * 64;
  if (idx >= total) return;
  int x = idx & 63;
  int co = (idx >> 6) % CO;
  int b = idx / (64 * CO);
  const float* ip = in + (size_t)b * CI * 64;
  const float* wp = w + (size_t)co * CI * 5;
  float acc = bias[co];
  for (int ci = 0; ci < CI; ++ci) {
    const float* ir = ip + ci * 64;
    const float* wr_ = wp + ci * 5;
#pragma unroll
    for (int k = 0; k < 5; ++k) {
      int xx = x + k - 2;
      if (xx >= 0 && xx < 64) acc += ir[xx] * wr_[k];
    }
  }
  out[idx] = fmaxf(acc, 0.f);
}

// ---------------------------------------------------------------- conv2d 3x3 pad=1 + relu (scalar; s1 only)
template <int CI, int CIC>
__global__ __launch_bounds__(256) void conv3x3_relu_k(
    const float* __restrict__ in, const float* __restrict__ w,
    const float* __restrict__ bias, float* __restrict__ out, int CO) {
  __shared__ float in_t[CIC][18][20];
  __shared__ float w_t[CIC][16][12];
  int t = threadIdx.x;
  int co_l = t & 15;
  int g = t >> 4;
  int gy = g >> 2, gx = g & 3;
  int y0 = (blockIdx.x >> 2) * 16, x0 = (blockIdx.x & 3) * 16;
  int co = blockIdx.y * 16 + co_l;
  int b = blockIdx.z;
  float acc[16];
#pragma unroll
  for (int i = 0; i < 16; ++i) acc[i] = 0.f;

  for (int cib = 0; cib < CI / CIC; ++cib) {
    int ci0 = cib * CIC;
    for (int s = t; s < CIC * 324; s += 256) {
      int ci = s / 324;
      int r = s - ci * 324;
      int iy = r / 18, ix = r - iy * 18;
      int gyy = y0 + iy - 1, gxx = x0 + ix - 1;
      float v = 0.f;
      if (gyy >= 0 && gyy < 64 && gxx >= 0 && gxx < 64)
        v = in[((size_t)b * CI + ci0 + ci) * 4096 + gyy * 64 + gxx];
      in_t[ci][iy][ix] = v;
    }
    for (int s = t; s < CIC * 144; s += 256) {
      int ci = s / 144;
      int r = s - ci * 144;
      int cw = r / 9, k = r - cw * 9;
      w_t[ci][cw][k] = w[((size_t)(blockIdx.y * 16 + cw) * CI + ci0 + ci) * 9 + k];
    }
    __syncthreads();
    for (int ci = 0; ci < CIC; ++ci) {
      float wv[9];
#pragma unroll
      for (int k = 0; k < 9; ++k) wv[k] = w_t[ci][co_l][k];
      float pin[36];
#pragma unroll
      for (int r6 = 0; r6 < 6; ++r6)
#pragma unroll
        for (int c6 = 0; c6 < 6; ++c6)
          pin[r6 * 6 + c6] = in_t[ci][4 * gy + r6][4 * gx + c6];
#pragma unroll
      for (int py = 0; py < 4; ++py)
#pragma unroll
        for (int px = 0; px < 4; ++px) {
          float s_ = acc[py * 4 + px];
#pragma unroll
          for (int ky = 0; ky < 3; ++ky)
#pragma unroll
            for (int kx = 0; kx < 3; ++kx)
              s_ += pin[(py + ky) * 6 + (px + kx)] * wv[ky * 3 + kx];
          acc[py * 4 + px] = s_;
        }
    }
    __syncthreads();
  }
  float bv = bias[co];
#pragma unroll
  for (int py = 0; py < 4; ++py)
#pragma unroll
    for (int px = 0; px < 4; ++px)
      out[((size_t)b * CO + co) * 4096 + (size_t)(y0 + 4 * gy + py) * 64 +
          (x0 + 4 * gx + px)] = fmaxf(acc[py * 4 + px] + bv, 0.f);
}

// ---------------------------------------------------------------- w_f transpose (256,260)->(260,256)
__global__ __launch_bounds__(256) void transpose_wf_k(const float* __restrict__ wf,
                                                      float* __restrict__ wfT) {
  int idx = blockIdx.x * 256 + threadIdx.x;
  if (idx >= 256 * 260) return;
  int co = idx / 260, c = idx - co * 260;
  wfT[c * 256 + co] = wf[idx];
}

// ---------------------------------------------------------------- w_p -> fp16 WT_hi/WT_lo [g*81+tap][co][ci%32]
__global__ __launch_bounds__(256) void transpose_wp_k(const float* __restrict__ wp,
                                                      u16* __restrict__ wth,
                                                      u16* __restrict__ wtl) {
  int s = blockIdx.x;  // 0..647 = g*81 + tap
  int g = s / 81, t = s - g * 81;
  int co = threadIdx.x;
  u16 th[32], tl[32];
#pragma unroll
  for (int c = 0; c < 32; ++c) {
    float f = wp[((size_t)co * 256 + g * 32 + c) * 81 + t];
    u16 h = f2h(f);
    th[c] = h;
    tl[c] = f2h(f - h2f(h));
  }
  ushort4* dh = (ushort4*)(wth + ((size_t)s * 256 + co) * 32);
  ushort4* dl = (ushort4*)(wtl + ((size_t)s * 256 + co) * 32);
#pragma unroll
  for (int q = 0; q < 8; ++q) {
    dh[q] = make_ushort4(th[4 * q], th[4 * q + 1], th[4 * q + 2], th[4 * q + 3]);
    dl[q] = make_ushort4(tl[4 * q], tl[4 * q + 1], tl[4 * q + 2], tl[4 * q + 3]);
  }
}

// ---------------------------------------------------------------- w3 (CO,CI,3,3) -> bf16 [g*9+tap][co][32] hi/lo
template <int CO, int NCHUNK>
__global__ __launch_bounds__(256) void transpose_w3_k(const float* __restrict__ w,
                                                      u16* __restrict__ wh,
                                                      u16* __restrict__ wl) {
  int tab = blockIdx.x;  // NCHUNK*9
  int g = tab / 9, tap = tab - g * 9;
  int co = threadIdx.x;
  if (co >= CO) return;
  constexpr int CI = NCHUNK * 32;
  u16 th[32], tl[32];
#pragma unroll
  for (int c = 0; c < 32; ++c) {
    float f = w[((size_t)co * CI + g * 32 + c) * 9 + tap];
    u16 h = f2bf(f);
    th[c] = h;
    tl[c] = f2bf(f - bf2f(h));
  }
  ushort4* dh = (ushort4*)(wh + ((size_t)tab * CO + co) * 32);
  ushort4* dl = (ushort4*)(wl + ((size_t)tab * CO + co) * 32);
#pragma unroll
  for (int q = 0; q < 8; ++q) {
    dh[q] = make_ushort4(th[4 * q], th[4 * q + 1], th[4 * q + 2], th[4 * q + 3]);
    dl[q] = make_ushort4(tl[4 * q], tl[4 * q + 1], tl[4 * q + 2], tl[4 * q + 3]);
  }
}

// ---------------------------------------------------------------- conv3x3 pad=1 s=1 via MFMA bf16 hi/lo 3-pass + relu
// (round-5 proven version)
template <int WM, int WN, int NCHUNK, int CO>
__global__ __launch_bounds__(512) void conv3x3_mfma_k(const float* __restrict__ in,
                                                      const u16* __restrict__ Wh,
                                                      const u16* __restrict__ Wl,
                                                      const float* __restrict__ bias,
                                                      float* __restrict__ out) {
  constexpr int CI = NCHUNK * 32;
  constexpr int ROWS = WM + 2;
  constexpr int KSTEPS = NCHUNK * 9;
  constexpr int NSTEPS = 3 * KSTEPS;
  constexpr int NV4 = CO / 128;
  __shared__ __align__(16) char lds_a[ROWS * 66 * 80];
  __shared__ __align__(16) char lds_b[2][CO * 80];
  const int tid = threadIdx.x;
  const int b = blockIdx.y;
  const int y0 = blockIdx.x * WM;
  const int w = tid >> 6, l = tid & 63;
  const int wm = w / WN, wn = w % WN;
  const int kb = l >> 4, il = l & 15;

  int abase[4];
#pragma unroll
  for (int mb = 0; mb < 4; ++mb) {
    int lp = (wm * 4 + mb) * 16 + il;
    int ly = lp >> 6, lx = lp & 63;
    abase[mb] = (ly * 66 + lx) * 80 + kb * 16;
  }
  int bbase[4];
#pragma unroll
  for (int nbi = 0; nbi < 4; ++nbi)
    bbase[nbi] = (wn * 64 + nbi * 16 + il) * 80 + kb * 16;

  f32x4 acc[4][4];
#pragma unroll
  for (int mb = 0; mb < 4; ++mb)
#pragma unroll
    for (int nbi = 0; nbi < 4; ++nbi) {
      f32x4 z = {0.f, 0.f, 0.f, 0.f};
      acc[mb][nbi] = z;
    }

  const float* Fb = in + (size_t)b * CI * 4096;
  float4 nb[NV4];

  auto stageA = [&](int g, int plane) {
    const float* src = Fb + (size_t)g * 32 * 4096;
    for (int s = tid; s < ROWS * 66 * 8; s += 512) {
      int ciq = s & 7;
      int rest = s >> 3;
      int r = rest / 66, x = rest - r * 66;
      int row = y0 - 1 + r, col = x - 1;
      float a0 = 0.f, a1 = 0.f, a2 = 0.f, a3 = 0.f;
      if (row >= 0 && row < 64 && col >= 0 && col < 64) {
        const float* p = src + (size_t)(ciq * 4) * 4096 + row * 64 + col;
        a0 = p[0];
        a1 = p[4096];
        a2 = p[8192];
        a3 = p[12288];
      }
      u16 e0, e1, e2, e3;
      if (plane == 0) {
        e0 = f2bf(a0); e1 = f2bf(a1); e2 = f2bf(a2); e3 = f2bf(a3);
      } else {
        u16 h0 = f2bf(a0), h1 = f2bf(a1), h2 = f2bf(a2), h3 = f2bf(a3);
        e0 = f2bf(a0 - bf2f(h0)); e1 = f2bf(a1 - bf2f(h1));
        e2 = f2bf(a2 - bf2f(h2)); e3 = f2bf(a3 - bf2f(h3));
      }
      *(ushort4*)(lds_a + (r * 66 + x) * 80 + ciq * 8) = make_ushort4(e0, e1, e2, e3);
    }
  };
  auto prefB = [&](int stepn) {
    int within = stepn % KSTEPS;
    const u16* W = (stepn >= 2 * KSTEPS) ? Wl : Wh;
    const char* p = (const char*)W + (size_t)within * CO * 64;
#pragma unroll
    for (int q = 0; q < NV4; ++q) nb[q] = *(const float4*)(p + (tid + q * 512) * 16);
  };
  auto writeB = [&](int buf) {
#pragma unroll
    for (int q = 0; q < NV4; ++q) {
      int u = tid + q * 512;
      *(float4*)(&lds_b[buf][(u >> 2) * 80 + (u & 3) * 16]) = nb[q];
    }
  };

  stageA(0, 0);
  prefB(0);
  writeB(0);

  int step = 0;
  for (int pass = 0; pass < 3; ++pass) {
    for (int g = 0; g < NCHUNK; ++g) {
      for (int tap = 0; tap < 9; ++tap, ++step) {
        __syncthreads();
        if (step + 1 < NSTEPS) prefB(step + 1);
        int ky = tap / 3, kx = tap - ky * 3;
        int koff = (ky * 66 + kx) * 80;
        int bsel = step & 1;
        bf16x8 av[4], bv[4];
#pragma unroll
        for (int mb = 0; mb < 4; ++mb)
          av[mb] = *(const bf16x8*)(lds_a + abase[mb] + koff);
#pragma unroll
        for (int nbi = 0; nbi < 4; ++nbi)
          bv[nbi] = *(const bf16x8*)(&lds_b[bsel][bbase[nbi]]);
#pragma unroll
        for (int mb = 0; mb < 4; ++mb)
#pragma unroll
          for (int nbi = 0; nbi < 4; ++nbi)
            acc[mb][nbi] = __builtin_amdgcn_mfma_f32_16x16x32_bf16(
                av[mb], bv[nbi], acc[mb][nbi], 0, 0, 0);
        if (step + 1 < NSTEPS) writeB((step + 1) & 1);
        if (tap == 8 && step + 1 < NSTEPS) {
          __syncthreads();
          int ns = step + 1;
          int npass = ns / KSTEPS;
          int ng = (ns % KSTEPS) / 9;
          stageA(ng, (npass == 1) ? 1 : 0);
        }
      }
    }
  }

  const int p0 = y0 * 64;
#pragma unroll
  for (int mb = 0; mb < 4; ++mb) {
    int pixb = p0 + (wm * 4 + mb) * 16 + kb * 4;
#pragma unroll
    for (int nbi = 0; nbi < 4; ++nbi) {
      int co = wn * 64 + nbi * 16 + il;
      float bv_ = bias[co];
      f32x4 a = acc[mb][nbi];
      float4 o = make_float4(fmaxf(a[0] + bv_, 0.f), fmaxf(a[1] + bv_, 0.f),
                             fmaxf(a[2] + bv_, 0.f), fmaxf(a[3] + bv_, 0.f));
      *(float4*)(out + (size_t)(b * CO + co) * 4096 + pixb) = o;
    }
  }
}

// ---------------------------------------------------------------- 1x1 fusion conv, fp32 IN-PLACE
__global__ __launch_bounds__(256) void fuse1x1_k(const float* __restrict__ t3,
                                                 const float* __restrict__ wfT,
                                                 const float* __restrict__ bf,
                                                 float* __restrict__ a) {
  __shared__ float in_t[260][32];
  int t = threadIdx.x;
  int b = blockIdx.x >> 7;
  int p0 = (blockIdx.x & 127) * 32;
  for (int s = t; s < 260 * 32; s += 256) {
    int c = s >> 5, pp = s & 31;
    float v;
    if (c < 4)
      v = t3[(size_t)b * 16384 + c * 4096 + p0 + pp];
    else
      v = a[((size_t)b * 256 + (c - 4)) * 4096 + p0 + pp];
    in_t[c][pp] = v;
  }
  __syncthreads();
  int co = t;
  float acc[32];
#pragma unroll
  for (int pp = 0; pp < 32; ++pp) acc[pp] = 0.f;
  for (int c = 0; c < 260; ++c) {
    float wv = wfT[c * 256 + co];
#pragma unroll
    for (int pp = 0; pp < 32; ++pp) acc[pp] += wv * in_t[c][pp];
  }
  float bv = bf[co];
#pragma unroll
  for (int pp = 0; pp < 32; ++pp)
    a[((size_t)b * 256 + co) * 4096 + p0 + pp] = acc[pp] + bv;
}

// ---------------------------------------------------------------- 9x9 s2 conv, MFMA fp16 2-pass
// A single fp16 plane in LDS (parity-split); B fp16 hi/lo global->regs.
// Per chunk g: stage A once -> 81 taps x {A*Bh + A*Bl} (32 MFMA / 4 A-reads).
__global__ __launch_bounds__(512) void conv9x9_mfma_k(const float* __restrict__ fused,
                                                      const u16* __restrict__ WTh,
                                                      const u16* __restrict__ WTl,
                                                      const float* __restrict__ bias,
                                                      float* __restrict__ praw) {
  constexpr int APLANE = 19 * 32 * 80;  // 48640 B per parity half-plane
  __shared__ __align__(16) char lds_a[2 * APLANE];   // 97280
  const int tid = threadIdx.x;
  const int b = blockIdx.y, tile = blockIdx.x;
  const int p0 = tile * 128;
  const int oy0 = p0 / 28;
  const int w = tid >> 6, l = tid & 63;
  const int wm = w >> 2, wn = w & 3;
  const int kb = l >> 4, il = l & 15;

  int abase[4];
#pragma unroll
  for (int mb = 0; mb < 4; ++mb) {
    int p = p0 + (wm * 4 + mb) * 16 + il;
    int oy = p / 28, ox = p - oy * 28;
    abase[mb] = (2 * (oy - oy0)) * 2560 + ox * 80 + kb * 16;
  }
  int boff[4];  // byte offset within one tap's 16384B weight block
#pragma unroll
  for (int nbi = 0; nbi < 4; ++nbi)
    boff[nbi] = (wn * 64 + nbi * 16 + il) * 64 + kb * 16;

  f32x4 acc[4][4];
#pragma unroll
  for (int mb = 0; mb < 4; ++mb)
#pragma unroll
    for (int nbi = 0; nbi < 4; ++nbi) {
      f32x4 z = {0.f, 0.f, 0.f, 0.f};
      acc[mb][nbi] = z;
    }

  const float* Fb = fused + (size_t)b * 256 * 4096;
  const char* WhB = (const char*)WTh;
  const char* WlB = (const char*)WTl;

  auto stageA = [&](int g) {
    const float* src = Fb + (size_t)g * 32 * 4096;
    for (int s = tid; s < 19 * 63 * 8; s += 512) {
      int ciq = s / 1197;
      int rem = s - ciq * 1197;
      int r = rem / 63, t63 = rem - r * 63;
      int x2 = (t63 < 32) ? 2 * t63 : 2 * (t63 - 32) + 1;  // parity-major lane map
      int iy = 2 * oy0 + r;
      float a0 = 0.f, a1 = 0.f, a2 = 0.f, a3 = 0.f;
      if (iy < 64) {
        const float* pp0 = src + (size_t)(ciq * 4) * 4096 + iy * 64 + x2;
        a0 = pp0[0];
        a1 = pp0[4096];
        a2 = pp0[8192];
        a3 = pp0[12288];
      }
      u16 e0 = f2h(a0), e1 = f2h(a1), e2 = f2h(a2), e3 = f2h(a3);
      int off = (x2 & 1) * APLANE + (r * 32 + (x2 >> 1)) * 80 + ciq * 8;
      *(ushort4*)(lds_a + off) = make_ushort4(e0, e1, e2, e3);
    }
  };

  for (int g = 0; g < 8; ++g) {
    __syncthreads();           // all waves done reading previous chunk's A
    stageA(g);
    __syncthreads();
#pragma unroll 3
    for (int t = 0; t < 81; ++t) {
      const char* pb = WhB + (size_t)(g * 81 + t) * 16384;
      const char* pl = WlB + (size_t)(g * 81 + t) * 16384;
      f16x8 bh[4], bl[4];
#pragma unroll
      for (int nbi = 0; nbi < 4; ++nbi) {
        bh[nbi] = *(const f16x8*)(pb + boff[nbi]);
        bl[nbi] = *(const f16x8*)(pl + boff[nbi]);
      }
      int ky = t / 9, kx = t - ky * 9;
      int toff = (kx & 1) * APLANE + ky * 2560 + (kx >> 1) * 80;
      f16x8 av[4];
#pragma unroll
      for (int mb = 0; mb < 4; ++mb)
        av[mb] = *(const f16x8*)(lds_a + abase[mb] + toff);
#pragma unroll
      for (int mb = 0; mb < 4; ++mb)
#pragma unroll
        for (int nbi = 0; nbi < 4; ++nbi) {
          acc[mb][nbi] = __builtin_amdgcn_mfma_f32_16x16x32_f16(
              av[mb], bh[nbi], acc[mb][nbi], 0, 0, 0);
          acc[mb][nbi] = __builtin_amdgcn_mfma_f32_16x16x32_f16(
              av[mb], bl[nbi], acc[mb][nbi], 0, 0, 0);
        }
    }
  }

#pragma unroll
  for (int mb = 0; mb < 4; ++mb) {
    int pixb = p0 + (wm * 4 + mb) * 16 + kb * 4;
    if (pixb < 784) {
#pragma unroll
      for (int nbi = 0; nbi < 4; ++nbi) {
        int co = wn * 64 + nbi * 16 + il;
        float bv_ = bias[co];
        f32x4 a = acc[mb][nbi];
        float4 o = make_float4(a[0] + bv_, a[1] + bv_, a[2] + bv_, a[3] + bv_);
        *(float4*)(praw + (size_t)(b * 256 + co) * 784 + pixb) = o;
      }
    }
  }
}

// ---------------------------------------------------------------- capsule squash: p(B,256,784) -> u(B,25088,8)
__global__ __launch_bounds__(256) void squash_caps_k(const float* __restrict__ p,
                                                     float* __restrict__ u) {
  int idx = blockIdx.x * 256 + threadIdx.x;
  if (idx >= BSZ * 25088) return;
  int b = idx / 25088;
  int cap = idx - b * 25088;
  int prim = cap / 784, pix = cap - prim * 784;
  const float* pp = p + ((size_t)b * 256 + prim * 8) * 784 + pix;
  float x[8];
  float sn = 0.f;
#pragma unroll
  for (int d = 0; d < 8; ++d) {
    x[d] = pp[(size_t)d * 784];
    sn += x[d] * x[d];
  }
  float scale = sn / ((1.f + sn) * sqrtf(sn + 1e-8f));
  float4 r0 = {x[0] * scale, x[1] * scale, x[2] * scale, x[3] * scale};
  float4 r1 = {x[4] * scale, x[5] * scale, x[6] * scale, x[7] * scale};
  float4* dst = (float4*)(u + (size_t)idx * 8);
  dst[0] = r0;
  dst[1] = r1;
}

// ---------------------------------------------------------------- u_hat = einsum('iodk,bik->biod')
__global__ __launch_bounds__(256) void uhat_k(const float* __restrict__ u,
                                              const float* __restrict__ w_r,
                                              float* __restrict__ u_hat) {
  int i = blockIdx.x * 256 + threadIdx.x;  // 25088
  int b = blockIdx.y;
  const float4* up = (const float4*)(u + ((size_t)b * 25088 + i) * 8);
  float4 ua = up[0], ub = up[1];
  const float4* wr = (const float4*)(w_r + (size_t)i * 256);
  float res[32];
#pragma unroll
  for (int od = 0; od < 32; ++od) {
    float4 wa = wr[od * 2], wb = wr[od * 2 + 1];
    res[od] = wa.x * ua.x + wa.y * ua.y + wa.z * ua.z + wa.w * ua.w +
              wb.x * ub.x + wb.y * ub.y + wb.z * ub.z + wb.w * ub.w;
  }
  float4* dst = (float4*)(u_hat + ((size_t)b * 25088 + i) * 32);
#pragma unroll
  for (int q = 0; q < 8; ++q)
    dst[q] = make_float4(res[4 * q], res[4 * q + 1], res[4 * q + 2], res[4 * q + 3]);
}

// ---------------------------------------------------------------- routing: partial s_j per (b,seg)
__global__ __launch_bounds__(256) void route_sj_k(const float* __restrict__ u_hat,
                                                  const float* __restrict__ b_ij,
                                                  float* __restrict__ sj_part, int iter) {
  int b = blockIdx.x;
  int seg = blockIdx.y;
  int t = threadIdx.x;
  float acc[32];
#pragma unroll
  for (int j = 0; j < 32; ++j) acc[j] = 0.f;
  int i0 = seg * 3136;
  for (int i = i0 + t; i < i0 + 3136; i += 256) {
    float c0 = 0.5f, c1 = 0.5f;
    if (iter > 0) {
      float b0 = b_ij[((size_t)b * 25088 + i) * 2 + 0];
      float b1 = b_ij[((size_t)b * 25088 + i) * 2 + 1];
      float m = fmaxf(b0, b1);
      float e0 = expf(b0 - m), e1 = expf(b1 - m);
      float inv = 1.f / (e0 + e1);
      c0 = e0 * inv;
      c1 = e1 * inv;
    }
    const float4* uh = (const float4*)(u_hat + ((size_t)b * 25088 + i) * 32);
#pragma unroll
    for (int q = 0; q < 4; ++q) {
      float4 va = uh[q];
      acc[4 * q + 0] += c0 * va.x;
      acc[4 * q + 1] += c0 * va.y;
      acc[4 * q + 2] += c0 * va.z;
      acc[4 * q + 3] += c0 * va.w;
      float4 vb = uh[4 + q];
      acc[16 + 4 * q + 0] += c1 * vb.x;
      acc[16 + 4 * q + 1] += c1 * vb.y;
      acc[16 + 4 * q + 2] += c1 * vb.z;
      acc[16 + 4 * q + 3] += c1 * vb.w;
    }
  }
#pragma unroll
  for (int j = 0; j < 32; ++j) {
    acc[j] += __shfl_down(acc[j], 32);
    acc[j] += __shfl_down(acc[j], 16);
    acc[j] += __shfl_down(acc[j], 8);
    acc[j] += __shfl_down(acc[j], 4);
    acc[j] += __shfl_down(acc[j], 2);
    acc[j] += __shfl_down(acc[j], 1);
  }
  __shared__ float red[4][32];
  int wave = t >> 6, lane = t & 63;
  if (lane == 0) {
#pragma unroll
    for (int j = 0; j < 32; ++j) red[wave][j] = acc[j];
  }
  __syncthreads();
  if (t < 32) {
    float s = red[0][t] + red[1][t] + red[2][t] + red[3][t];
    sj_part[((size_t)b * 8 + seg) * 32 + t] = s;
  }
}

// ---------------------------------------------------------------- routing: finalize v
__global__ __launch_bounds__(256) void route_fin_k(const float* __restrict__ sj_part,
                                                   float* __restrict__ v,
                                                   float* __restrict__ out, int final_it) {
  int idx = blockIdx.x * 256 + threadIdx.x;
  if (idx >= BSZ * 32) return;
  int b = idx >> 5, j = idx & 31;
  float s = 0.f;
#pragma unroll
  for (int seg = 0; seg < 8; ++seg) s += sj_part[((size_t)b * 8 + seg) * 32 + j];
  float sn = s * s;
  float vv = sn * s / ((1.f + sn) * sqrtf(sn + 1e-8f));
  v[idx] = vv;
  if (final_it) out[idx] = fabsf(vv);
}

// ---------------------------------------------------------------- routing: b_ij update
__global__ __launch_bounds__(256) void route_upd_k(const float* __restrict__ u_hat,
                                                   const float* __restrict__ v,
                                                   float* __restrict__ b_ij, int first) {
  int i = blockIdx.x * 256 + threadIdx.x;  // 25088
  int b = blockIdx.y;
  const float4* uh = (const float4*)(u_hat + ((size_t)b * 25088 + i) * 32);
  const float4* vp = (const float4*)(v + b * 32);
  float e0 = 0.f, e1 = 0.f;
#pragma unroll
  for (int q = 0; q < 4; ++q) {
    float4 a = uh[q], wv = vp[q];
    e0 += a.x * wv.x + a.y * wv.y + a.z * wv.z + a.w * wv.w;
    float4 a2 = uh[4 + q], w2 = vp[4 + q];
    e1 += a2.x * w2.x + a2.y * w2.y + a2.z * w2.z + a2.w * w2.w;
  }
  size_t o = ((size_t)b * 25088 + i) * 2;
  if (first) {
    b_ij[o + 0] = e0;
    b_ij[o + 1] = e1;
  } else {
    b_ij[o + 0] += e0;
    b_ij[o + 1] += e1;
  }
}

// ================================================================ launch
extern "C" void kernel_launch(void* const* d_in, const int* in_sizes, int n_in,
                              void* d_out, int out_size, void* d_ws, size_t ws_size,
                              hipStream_t stream) {
  (void)in_sizes; (void)n_in; (void)out_size;
  const float* x    = (const float*)d_in[0];
  const float* w_t1 = (const float*)d_in[1];
  const float* b_t1 = (const float*)d_in[2];
  const float* w_t2 = (const float*)d_in[3];
  const float* b_t2 = (const float*)d_in[4];
  const float* w_t3 = (const float*)d_in[5];
  const float* b_t3 = (const float*)d_in[6];
  const float* w_s1 = (const float*)d_in[7];
  const float* b_s1 = (const float*)d_in[8];
  const float* w_s2 = (const float*)d_in[9];
  const float* b_s2 = (const float*)d_in[10];
  const float* w_s3 = (const float*)d_in[11];
  const float* b_s3 = (const float*)d_in[12];
  const float* w_f  = (const float*)d_in[13];
  const float* b_f  = (const float*)d_in[14];
  const float* w_p  = (const float*)d_in[15];
  const float* b_p  = (const float*)d_in[16];
  const float* w_r  = (const float*)d_in[17];
  float* out = (float*)d_out;

  char* ws = (char*)d_ws;
  if (ws_size < 238854144ull) return;
  // region 0: fused / uhat
  float* fused = (float*)(ws + 0);
  float* uhat  = (float*)(ws + 0);
  // region 1 (134,217,728): s2q -> praw/u/b_ij
  float* s2q   = (float*)(ws + 134217728);
  float* praw  = (float*)(ws + 134217728);
  float* u     = (float*)(ws + 159907840);
  float* b_ij  = (float*)(ws + 185597952);
  // region 2 (201,326,592): s1 -> t1/t2/t3/wTh/wTl
  float* s1    = (float*)(ws + 201326592);
  float* t1    = (float*)(ws + 201326592);
  float* t2    = (float*)(ws + 201850880);
  float* t3    = (float*)(ws + 202899456);
  u16*   wTh   = (u16*)  (ws + 204996608);
  u16*   wTl   = (u16*)  (ws + 215613440);
  // tail (234,881,024): persistent small tables
  u16*   w3a_h = (u16*)  (ws + 234881024);
  u16*   w3a_l = (u16*)  (ws + 235028480);
  u16*   w3b_h = (u16*)  (ws + 235175936);
  u16*   w3b_l = (u16*)  (ws + 235765760);
  float* wfT   = (float*)(ws + 236355584);
  float* sjp   = (float*)(ws + 236621824);
  float* vbuf  = (float*)(ws + 236654592);

  // small weight tables (tail region -- never clobbered)
  transpose_w3_k<128, 2><<<18, 256, 0, stream>>>(w_s2, w3a_h, w3a_l);
  transpose_w3_k<256, 4><<<36, 256, 0, stream>>>(w_s3, w3b_h, w3b_l);
  transpose_wf_k<<<261, 256, 0, stream>>>(w_f, wfT);

  // spectral: s1 scalar conv, then s2 MFMA conv (consumes s1)
  conv3x3_relu_k<1, 1><<<dim3(16, 4, BSZ), 256, 0, stream>>>(x, w_s1, b_s1, s1, 64);
  conv3x3_mfma_k<4, 2, 2, 128><<<dim3(16, BSZ), 512, 0, stream>>>(s1, w3a_h, w3a_l, b_s2, s2q);

  // s1 now dead: temporal branch + 9x9 weight tables move into its region
  conv1d_relu_k<<<512, 256, 0, stream>>>(x, w_t1, b_t1, t1, 64, 64);
  conv1d_relu_k<<<1024, 256, 0, stream>>>(t1, w_t2, b_t2, t2, 64, 128);
  conv1d_relu_k<<<2048, 256, 0, stream>>>(t2, w_t3, b_t3, t3, 128, 256);
  transpose_wp_k<<<648, 256, 0, stream>>>(w_p, wTh, wTl);

  // s3 MFMA conv -> fused
  conv3x3_mfma_k<2, 4, 4, 256><<<dim3(32, BSZ), 512, 0, stream>>>(s2q, w3b_h, w3b_l, b_s3, fused);

  // fusion fp32 in-place
  fuse1x1_k<<<4096, 256, 0, stream>>>(t3, wfT, b_f, fused);

  // primary capsules via MFMA fp16 2-pass (praw over dead s2q)
  conv9x9_mfma_k<<<dim3(7, BSZ), 512, 0, stream>>>(fused, wTh, wTl, b_p, praw);
  squash_caps_k<<<3136, 256, 0, stream>>>(praw, u);

  // u_hat (overwrites fused region)
  uhat_k<<<dim3(98, BSZ), 256, 0, stream>>>(u, w_r, uhat);

  // dynamic routing, 3 iterations
  route_sj_k<<<dim3(BSZ, 8), 256, 0, stream>>>(uhat, b_ij, sjp, 0);
  route_fin_k<<<4, 256, 0, stream>>>(sjp, vbuf, out, 0);
  route_upd_k<<<dim3(98, BSZ), 256, 0, stream>>>(uhat, vbuf, b_ij, 1);

  route_sj_k<<<dim3(BSZ, 8), 256, 0, stream>>>(uhat, b_ij, sjp, 1);
  route_fin_k<<<4, 256, 0, stream>>>(sjp, vbuf, out, 0);
  route_upd_k<<<dim3(98, BSZ), 256, 0, stream>>>(uhat, vbuf, b_ij, 0);

  route_sj_k<<<dim3(BSZ, 8), 256, 0, stream>>>(uhat, b_ij, sjp, 2);
  route_fin_k<<<4, 256, 0, stream>>>(sjp, vbuf, out, 1);
}

// Round 15
// 1823.568 us; speedup vs baseline: 1.2105x; 1.0130x over previous
//
#include <hip/hip_runtime.h>
#include <math.h>

// STCCapsNet forward. B=32, C=1, H=W=64, HP=WP=28, IN_CAPS=25088, OUT 32x2x16.
// Round 15: conv9x9 -> 1024-thread blocks, 16 waves (2M x 8N, wave = 4mb x 2nbi).
// 4 waves/SIMD hides B-load (L2) latency; A-read LDS traffic 64 b128/tap; B L2
// traffic unchanged. Numerics identical to r14 (A fp16 single, B fp16 hi/lo 2-pass).

#define BSZ 32

typedef unsigned short u16;
using bf16x8 = __attribute__((ext_vector_type(8))) short;
using f16x8 = __attribute__((ext_vector_type(8))) _Float16;
using f32x4 = __attribute__((ext_vector_type(4))) float;

__device__ inline u16 f2bf(float f) {
  union { float f; unsigned u; } v; v.f = f;
  unsigned r = v.u + 0x7FFF + ((v.u >> 16) & 1);
  return (u16)(r >> 16);
}
__device__ inline float bf2f(u16 h) {
  union { unsigned u; float f; } v; v.u = ((unsigned)h) << 16;
  return v.f;
}
__device__ inline u16 f2h(float f) {
  union { _Float16 h; u16 u; } v; v.h = (_Float16)f;
  return v.u;
}
__device__ inline float h2f(u16 b) {
  union { u16 u; _Float16 h; } v; v.u = b;
  return (float)v.h;
}

// ---------------------------------------------------------------- conv1d k=5 pad=2 + relu
__global__ __launch_bounds__(256) void conv1d_relu_k(
    const float* __restrict__ in, const float* __restrict__ w,
    const float* __restrict__ bias, float* __restrict__ out, int CI, int CO) {
  int idx = blockIdx.x * 256 + threadIdx.x;
  int total = BSZ * CO * 64;
  if (idx >= total) return;
  int x = idx & 63;
  int co = (idx >> 6) % CO;
  int b = idx / (64 * CO);
  const float* ip = in + (size_t)b * CI * 64;
  const float* wp = w + (size_t)co * CI * 5;
  float acc = bias[co];
  for (int ci = 0; ci < CI; ++ci) {
    const float* ir = ip + ci * 64;
    const float* wr_ = wp + ci * 5;
#pragma unroll
    for (int k = 0; k < 5; ++k) {
      int xx = x + k - 2;
      if (xx >= 0 && xx < 64) acc += ir[xx] * wr_[k];
    }
  }
  out[idx] = fmaxf(acc, 0.f);
}

// ---------------------------------------------------------------- conv2d 3x3 pad=1 + relu (scalar; s1 only)
template <int CI, int CIC>
__global__ __launch_bounds__(256) void conv3x3_relu_k(
    const float* __restrict__ in, const float* __restrict__ w,
    const float* __restrict__ bias, float* __restrict__ out, int CO) {
  __shared__ float in_t[CIC][18][20];
  __shared__ float w_t[CIC][16][12];
  int t = threadIdx.x;
  int co_l = t & 15;
  int g = t >> 4;
  int gy = g >> 2, gx = g & 3;
  int y0 = (blockIdx.x >> 2) * 16, x0 = (blockIdx.x & 3) * 16;
  int co = blockIdx.y * 16 + co_l;
  int b = blockIdx.z;
  float acc[16];
#pragma unroll
  for (int i = 0; i < 16; ++i) acc[i] = 0.f;

  for (int cib = 0; cib < CI / CIC; ++cib) {
    int ci0 = cib * CIC;
    for (int s = t; s < CIC * 324; s += 256) {
      int ci = s / 324;
      int r = s - ci * 324;
      int iy = r / 18, ix = r - iy * 18;
      int gyy = y0 + iy - 1, gxx = x0 + ix - 1;
      float v = 0.f;
      if (gyy >= 0 && gyy < 64 && gxx >= 0 && gxx < 64)
        v = in[((size_t)b * CI + ci0 + ci) * 4096 + gyy * 64 + gxx];
      in_t[ci][iy][ix] = v;
    }
    for (int s = t; s < CIC * 144; s += 256) {
      int ci = s / 144;
      int r = s - ci * 144;
      int cw = r / 9, k = r - cw * 9;
      w_t[ci][cw][k] = w[((size_t)(blockIdx.y * 16 + cw) * CI + ci0 + ci) * 9 + k];
    }
    __syncthreads();
    for (int ci = 0; ci < CIC; ++ci) {
      float wv[9];
#pragma unroll
      for (int k = 0; k < 9; ++k) wv[k] = w_t[ci][co_l][k];
      float pin[36];
#pragma unroll
      for (int r6 = 0; r6 < 6; ++r6)
#pragma unroll
        for (int c6 = 0; c6 < 6; ++c6)
          pin[r6 * 6 + c6] = in_t[ci][4 * gy + r6][4 * gx + c6];
#pragma unroll
      for (int py = 0; py < 4; ++py)
#pragma unroll
        for (int px = 0; px < 4; ++px) {
          float s_ = acc[py * 4 + px];
#pragma unroll
          for (int ky = 0; ky < 3; ++ky)
#pragma unroll
            for (int kx = 0; kx < 3; ++kx)
              s_ += pin[(py + ky) * 6 + (px + kx)] * wv[ky * 3 + kx];
          acc[py * 4 + px] = s_;
        }
    }
    __syncthreads();
  }
  float bv = bias[co];
#pragma unroll
  for (int py = 0; py < 4; ++py)
#pragma unroll
    for (int px = 0; px < 4; ++px)
      out[((size_t)b * CO + co) * 4096 + (size_t)(y0 + 4 * gy + py) * 64 +
          (x0 + 4 * gx + px)] = fmaxf(acc[py * 4 + px] + bv, 0.f);
}

// ---------------------------------------------------------------- w_f transpose (256,260)->(260,256)
__global__ __launch_bounds__(256) void transpose_wf_k(const float* __restrict__ wf,
                                                      float* __restrict__ wfT) {
  int idx = blockIdx.x * 256 + threadIdx.x;
  if (idx >= 256 * 260) return;
  int co = idx / 260, c = idx - co * 260;
  wfT[c * 256 + co] = wf[idx];
}

// ---------------------------------------------------------------- w_p -> fp16 WT_hi/WT_lo [g*81+tap][co][ci%32]
__global__ __launch_bounds__(256) void transpose_wp_k(const float* __restrict__ wp,
                                                      u16* __restrict__ wth,
                                                      u16* __restrict__ wtl) {
  int s = blockIdx.x;  // 0..647 = g*81 + tap
  int g = s / 81, t = s - g * 81;
  int co = threadIdx.x;
  u16 th[32], tl[32];
#pragma unroll
  for (int c = 0; c < 32; ++c) {
    float f = wp[((size_t)co * 256 + g * 32 + c) * 81 + t];
    u16 h = f2h(f);
    th[c] = h;
    tl[c] = f2h(f - h2f(h));
  }
  ushort4* dh = (ushort4*)(wth + ((size_t)s * 256 + co) * 32);
  ushort4* dl = (ushort4*)(wtl + ((size_t)s * 256 + co) * 32);
#pragma unroll
  for (int q = 0; q < 8; ++q) {
    dh[q] = make_ushort4(th[4 * q], th[4 * q + 1], th[4 * q + 2], th[4 * q + 3]);
    dl[q] = make_ushort4(tl[4 * q], tl[4 * q + 1], tl[4 * q + 2], tl[4 * q + 3]);
  }
}

// ---------------------------------------------------------------- w3 (CO,CI,3,3) -> bf16 [g*9+tap][co][32] hi/lo
template <int CO, int NCHUNK>
__global__ __launch_bounds__(256) void transpose_w3_k(const float* __restrict__ w,
                                                      u16* __restrict__ wh,
                                                      u16* __restrict__ wl) {
  int tab = blockIdx.x;  // NCHUNK*9
  int g = tab / 9, tap = tab - g * 9;
  int co = threadIdx.x;
  if (co >= CO) return;
  constexpr int CI = NCHUNK * 32;
  u16 th[32], tl[32];
#pragma unroll
  for (int c = 0; c < 32; ++c) {
    float f = w[((size_t)co * CI + g * 32 + c) * 9 + tap];
    u16 h = f2bf(f);
    th[c] = h;
    tl[c] = f2bf(f - bf2f(h));
  }
  ushort4* dh = (ushort4*)(wh + ((size_t)tab * CO + co) * 32);
  ushort4* dl = (ushort4*)(wl + ((size_t)tab * CO + co) * 32);
#pragma unroll
  for (int q = 0; q < 8; ++q) {
    dh[q] = make_ushort4(th[4 * q], th[4 * q + 1], th[4 * q + 2], th[4 * q + 3]);
    dl[q] = make_ushort4(tl[4 * q], tl[4 * q + 1], tl[4 * q + 2], tl[4 * q + 3]);
  }
}

// ---------------------------------------------------------------- conv3x3 pad=1 s=1 via MFMA bf16 hi/lo 3-pass + relu
// (round-5 proven version)
template <int WM, int WN, int NCHUNK, int CO>
__global__ __launch_bounds__(512) void conv3x3_mfma_k(const float* __restrict__ in,
                                                      const u16* __restrict__ Wh,
                                                      const u16* __restrict__ Wl,
                                                      const float* __restrict__ bias,
                                                      float* __restrict__ out) {
  constexpr int CI = NCHUNK * 32;
  constexpr int ROWS = WM + 2;
  constexpr int KSTEPS = NCHUNK * 9;
  constexpr int NSTEPS = 3 * KSTEPS;
  constexpr int NV4 = CO / 128;
  __shared__ __align__(16) char lds_a[ROWS * 66 * 80];
  __shared__ __align__(16) char lds_b[2][CO * 80];
  const int tid = threadIdx.x;
  const int b = blockIdx.y;
  const int y0 = blockIdx.x * WM;
  const int w = tid >> 6, l = tid & 63;
  const int wm = w / WN, wn = w % WN;
  const int kb = l >> 4, il = l & 15;

  int abase[4];
#pragma unroll
  for (int mb = 0; mb < 4; ++mb) {
    int lp = (wm * 4 + mb) * 16 + il;
    int ly = lp >> 6, lx = lp & 63;
    abase[mb] = (ly * 66 + lx) * 80 + kb * 16;
  }
  int bbase[4];
#pragma unroll
  for (int nbi = 0; nbi < 4; ++nbi)
    bbase[nbi] = (wn * 64 + nbi * 16 + il) * 80 + kb * 16;

  f32x4 acc[4][4];
#pragma unroll
  for (int mb = 0; mb < 4; ++mb)
#pragma unroll
    for (int nbi = 0; nbi < 4; ++nbi) {
      f32x4 z = {0.f, 0.f, 0.f, 0.f};
      acc[mb][nbi] = z;
    }

  const float* Fb = in + (size_t)b * CI * 4096;
  float4 nb[NV4];

  auto stageA = [&](int g, int plane) {
    const float* src = Fb + (size_t)g * 32 * 4096;
    for (int s = tid; s < ROWS * 66 * 8; s += 512) {
      int ciq = s & 7;
      int rest = s >> 3;
      int r = rest / 66, x = rest - r * 66;
      int row = y0 - 1 + r, col = x - 1;
      float a0 = 0.f, a1 = 0.f, a2 = 0.f, a3 = 0.f;
      if (row >= 0 && row < 64 && col >= 0 && col < 64) {
        const float* p = src + (size_t)(ciq * 4) * 4096 + row * 64 + col;
        a0 = p[0];
        a1 = p[4096];
        a2 = p[8192];
        a3 = p[12288];
      }
      u16 e0, e1, e2, e3;
      if (plane == 0) {
        e0 = f2bf(a0); e1 = f2bf(a1); e2 = f2bf(a2); e3 = f2bf(a3);
      } else {
        u16 h0 = f2bf(a0), h1 = f2bf(a1), h2 = f2bf(a2), h3 = f2bf(a3);
        e0 = f2bf(a0 - bf2f(h0)); e1 = f2bf(a1 - bf2f(h1));
        e2 = f2bf(a2 - bf2f(h2)); e3 = f2bf(a3 - bf2f(h3));
      }
      *(ushort4*)(lds_a + (r * 66 + x) * 80 + ciq * 8) = make_ushort4(e0, e1, e2, e3);
    }
  };
  auto prefB = [&](int stepn) {
    int within = stepn % KSTEPS;
    const u16* W = (stepn >= 2 * KSTEPS) ? Wl : Wh;
    const char* p = (const char*)W + (size_t)within * CO * 64;
#pragma unroll
    for (int q = 0; q < NV4; ++q) nb[q] = *(const float4*)(p + (tid + q * 512) * 16);
  };
  auto writeB = [&](int buf) {
#pragma unroll
    for (int q = 0; q < NV4; ++q) {
      int u = tid + q * 512;
      *(float4*)(&lds_b[buf][(u >> 2) * 80 + (u & 3) * 16]) = nb[q];
    }
  };

  stageA(0, 0);
  prefB(0);
  writeB(0);

  int step = 0;
  for (int pass = 0; pass < 3; ++pass) {
    for (int g = 0; g < NCHUNK; ++g) {
      for (int tap = 0; tap < 9; ++tap, ++step) {
        __syncthreads();
        if (step + 1 < NSTEPS) prefB(step + 1);
        int ky = tap / 3, kx = tap - ky * 3;
        int koff = (ky * 66 + kx) * 80;
        int bsel = step & 1;
        bf16x8 av[4], bv[4];
#pragma unroll
        for (int mb = 0; mb < 4; ++mb)
          av[mb] = *(const bf16x8*)(lds_a + abase[mb] + koff);
#pragma unroll
        for (int nbi = 0; nbi < 4; ++nbi)
          bv[nbi] = *(const bf16x8*)(&lds_b[bsel][bbase[nbi]]);
#pragma unroll
        for (int mb = 0; mb < 4; ++mb)
#pragma unroll
          for (int nbi = 0; nbi < 4; ++nbi)
            acc[mb][nbi] = __builtin_amdgcn_mfma_f32_16x16x32_bf16(
                av[mb], bv[nbi], acc[mb][nbi], 0, 0, 0);
        if (step + 1 < NSTEPS) writeB((step + 1) & 1);
        if (tap == 8 && step + 1 < NSTEPS) {
          __syncthreads();
          int ns = step + 1;
          int npass = ns / KSTEPS;
          int ng = (ns % KSTEPS) / 9;
          stageA(ng, (npass == 1) ? 1 : 0);
        }
      }
    }
  }

  const int p0 = y0 * 64;
#pragma unroll
  for (int mb = 0; mb < 4; ++mb) {
    int pixb = p0 + (wm * 4 + mb) * 16 + kb * 4;
#pragma unroll
    for (int nbi = 0; nbi < 4; ++nbi) {
      int co = wn * 64 + nbi * 16 + il;
      float bv_ = bias[co];
      f32x4 a = acc[mb][nbi];
      float4 o = make_float4(fmaxf(a[0] + bv_, 0.f), fmaxf(a[1] + bv_, 0.f),
                             fmaxf(a[2] + bv_, 0.f), fmaxf(a[3] + bv_, 0.f));
      *(float4*)(out + (size_t)(b * CO + co) * 4096 + pixb) = o;
    }
  }
}

// ---------------------------------------------------------------- 1x1 fusion conv, fp32 IN-PLACE
__global__ __launch_bounds__(256) void fuse1x1_k(const float* __restrict__ t3,
                                                 const float* __restrict__ wfT,
                                                 const float* __restrict__ bf,
                                                 float* __restrict__ a) {
  __shared__ float in_t[260][32];
  int t = threadIdx.x;
  int b = blockIdx.x >> 7;
  int p0 = (blockIdx.x & 127) * 32;
  for (int s = t; s < 260 * 32; s += 256) {
    int c = s >> 5, pp = s & 31;
    float v;
    if (c < 4)
      v = t3[(size_t)b * 16384 + c * 4096 + p0 + pp];
    else
      v = a[((size_t)b * 256 + (c - 4)) * 4096 + p0 + pp];
    in_t[c][pp] = v;
  }
  __syncthreads();
  int co = t;
  float acc[32];
#pragma unroll
  for (int pp = 0; pp < 32; ++pp) acc[pp] = 0.f;
  for (int c = 0; c < 260; ++c) {
    float wv = wfT[c * 256 + co];
#pragma unroll
    for (int pp = 0; pp < 32; ++pp) acc[pp] += wv * in_t[c][pp];
  }
  float bv = bf[co];
#pragma unroll
  for (int pp = 0; pp < 32; ++pp)
    a[((size_t)b * 256 + co) * 4096 + p0 + pp] = acc[pp] + bv;
}

// ---------------------------------------------------------------- 9x9 s2 conv, MFMA fp16 2-pass, 16 waves
// A single fp16 plane in LDS (parity-split); B fp16 hi/lo global->regs.
// 1024 thr = 16 waves (2M x 8N); wave = 4 mb x 2 nbi. 4 waves/SIMD.
__global__ __launch_bounds__(1024) void conv9x9_mfma_k(const float* __restrict__ fused,
                                                       const u16* __restrict__ WTh,
                                                       const u16* __restrict__ WTl,
                                                       const float* __restrict__ bias,
                                                       float* __restrict__ praw) {
  constexpr int APLANE = 19 * 32 * 80;  // 48640 B per parity half-plane
  __shared__ __align__(16) char lds_a[2 * APLANE];   // 97280
  const int tid = threadIdx.x;
  const int b = blockIdx.y, tile = blockIdx.x;
  const int p0 = tile * 128;
  const int oy0 = p0 / 28;
  const int w = tid >> 6, l = tid & 63;
  const int wm = w >> 3, wn = w & 7;
  const int kb = l >> 4, il = l & 15;

  int abase[4];
#pragma unroll
  for (int mb = 0; mb < 4; ++mb) {
    int p = p0 + (wm * 4 + mb) * 16 + il;
    int oy = p / 28, ox = p - oy * 28;
    abase[mb] = (2 * (oy - oy0)) * 2560 + ox * 80 + kb * 16;
  }
  int boff[2];  // byte offset within one tap's 16384B weight block
#pragma unroll
  for (int nbi = 0; nbi < 2; ++nbi)
    boff[nbi] = (wn * 32 + nbi * 16 + il) * 64 + kb * 16;

  f32x4 acc[4][2];
#pragma unroll
  for (int mb = 0; mb < 4; ++mb)
#pragma unroll
    for (int nbi = 0; nbi < 2; ++nbi) {
      f32x4 z = {0.f, 0.f, 0.f, 0.f};
      acc[mb][nbi] = z;
    }

  const float* Fb = fused + (size_t)b * 256 * 4096;
  const char* WhB = (const char*)WTh;
  const char* WlB = (const char*)WTl;

  auto stageA = [&](int g) {
    const float* src = Fb + (size_t)g * 32 * 4096;
    for (int s = tid; s < 19 * 63 * 8; s += 1024) {
      int ciq = s / 1197;
      int rem = s - ciq * 1197;
      int r = rem / 63, t63 = rem - r * 63;
      int x2 = (t63 < 32) ? 2 * t63 : 2 * (t63 - 32) + 1;  // parity-major lane map
      int iy = 2 * oy0 + r;
      float a0 = 0.f, a1 = 0.f, a2 = 0.f, a3 = 0.f;
      if (iy < 64) {
        const float* pp0 = src + (size_t)(ciq * 4) * 4096 + iy * 64 + x2;
        a0 = pp0[0];
        a1 = pp0[4096];
        a2 = pp0[8192];
        a3 = pp0[12288];
      }
      u16 e0 = f2h(a0), e1 = f2h(a1), e2 = f2h(a2), e3 = f2h(a3);
      int off = (x2 & 1) * APLANE + (r * 32 + (x2 >> 1)) * 80 + ciq * 8;
      *(ushort4*)(lds_a + off) = make_ushort4(e0, e1, e2, e3);
    }
  };

  for (int g = 0; g < 8; ++g) {
    __syncthreads();           // all waves done reading previous chunk's A
    stageA(g);
    __syncthreads();
#pragma unroll 3
    for (int t = 0; t < 81; ++t) {
      const char* pb = WhB + (size_t)(g * 81 + t) * 16384;
      const char* pl = WlB + (size_t)(g * 81 + t) * 16384;
      f16x8 bh[2], bl[2];
#pragma unroll
      for (int nbi = 0; nbi < 2; ++nbi) {
        bh[nbi] = *(const f16x8*)(pb + boff[nbi]);
        bl[nbi] = *(const f16x8*)(pl + boff[nbi]);
      }
      int ky = t / 9, kx = t - ky * 9;
      int toff = (kx & 1) * APLANE + ky * 2560 + (kx >> 1) * 80;
      f16x8 av[4];
#pragma unroll
      for (int mb = 0; mb < 4; ++mb)
        av[mb] = *(const f16x8*)(lds_a + abase[mb] + toff);
#pragma unroll
      for (int mb = 0; mb < 4; ++mb)
#pragma unroll
        for (int nbi = 0; nbi < 2; ++nbi) {
          acc[mb][nbi] = __builtin_amdgcn_mfma_f32_16x16x32_f16(
              av[mb], bh[nbi], acc[mb][nbi], 0, 0, 0);
          acc[mb][nbi] = __builtin_amdgcn_mfma_f32_16x16x32_f16(
              av[mb], bl[nbi], acc[mb][nbi], 0, 0, 0);
        }
    }
  }

#pragma unroll
  for (int mb = 0; mb < 4; ++mb) {
    int pixb = p0 + (wm * 4 + mb) * 16 + kb * 4;
    if (pixb < 784) {
#pragma unroll
      for (int nbi = 0; nbi < 2; ++nbi) {
        int co = wn * 32 + nbi * 16 + il;
        float bv_ = bias[co];
        f32x4 a = acc[mb][nbi];
        float4 o = make_float4(a[0] + bv_, a[1] + bv_, a[2] + bv_, a[3] + bv_);
        *(float4*)(praw + (size_t)(b * 256 + co) * 784 + pixb) = o;
      }
    }
  }
}

// ---------------------------------------------------------------- capsule squash: p(B,256,784) -> u(B,25088,8)
__global__ __launch_bounds__(256) void squash_caps_k(const float* __restrict__ p,
                                                     float* __restrict__ u) {
  int idx = blockIdx.x * 256 + threadIdx.x;
  if (idx >= BSZ * 25088) return;
  int b = idx / 25088;
  int cap = idx - b * 25088;
  int prim = cap / 784, pix = cap - prim * 784;
  const float* pp = p + ((size_t)b * 256 + prim * 8) * 784 + pix;
  float x[8];
  float sn = 0.f;
#pragma unroll
  for (int d = 0; d < 8; ++d) {
    x[d] = pp[(size_t)d * 784];
    sn += x[d] * x[d];
  }
  float scale = sn / ((1.f + sn) * sqrtf(sn + 1e-8f));
  float4 r0 = {x[0] * scale, x[1] * scale, x[2] * scale, x[3] * scale};
  float4 r1 = {x[4] * scale, x[5] * scale, x[6] * scale, x[7] * scale};
  float4* dst = (float4*)(u + (size_t)idx * 8);
  dst[0] = r0;
  dst[1] = r1;
}

// ---------------------------------------------------------------- u_hat = einsum('iodk,bik->biod')
__global__ __launch_bounds__(256) void uhat_k(const float* __restrict__ u,
                                              const float* __restrict__ w_r,
                                              float* __restrict__ u_hat) {
  int i = blockIdx.x * 256 + threadIdx.x;  // 25088
  int b = blockIdx.y;
  const float4* up = (const float4*)(u + ((size_t)b * 25088 + i) * 8);
  float4 ua = up[0], ub = up[1];
  const float4* wr = (const float4*)(w_r + (size_t)i * 256);
  float res[32];
#pragma unroll
  for (int od = 0; od < 32; ++od) {
    float4 wa = wr[od * 2], wb = wr[od * 2 + 1];
    res[od] = wa.x * ua.x + wa.y * ua.y + wa.z * ua.z + wa.w * ua.w +
              wb.x * ub.x + wb.y * ub.y + wb.z * ub.z + wb.w * ub.w;
  }
  float4* dst = (float4*)(u_hat + ((size_t)b * 25088 + i) * 32);
#pragma unroll
  for (int q = 0; q < 8; ++q)
    dst[q] = make_float4(res[4 * q], res[4 * q + 1], res[4 * q + 2], res[4 * q + 3]);
}

// ---------------------------------------------------------------- routing: partial s_j per (b,seg)
__global__ __launch_bounds__(256) void route_sj_k(const float* __restrict__ u_hat,
                                                  const float* __restrict__ b_ij,
                                                  float* __restrict__ sj_part, int iter) {
  int b = blockIdx.x;
  int seg = blockIdx.y;
  int t = threadIdx.x;
  float acc[32];
#pragma unroll
  for (int j = 0; j < 32; ++j) acc[j] = 0.f;
  int i0 = seg * 3136;
  for (int i = i0 + t; i < i0 + 3136; i += 256) {
    float c0 = 0.5f, c1 = 0.5f;
    if (iter > 0) {
      float b0 = b_ij[((size_t)b * 25088 + i) * 2 + 0];
      float b1 = b_ij[((size_t)b * 25088 + i) * 2 + 1];
      float m = fmaxf(b0, b1);
      float e0 = expf(b0 - m), e1 = expf(b1 - m);
      float inv = 1.f / (e0 + e1);
      c0 = e0 * inv;
      c1 = e1 * inv;
    }
    const float4* uh = (const float4*)(u_hat + ((size_t)b * 25088 + i) * 32);
#pragma unroll
    for (int q = 0; q < 4; ++q) {
      float4 va = uh[q];
      acc[4 * q + 0] += c0 * va.x;
      acc[4 * q + 1] += c0 * va.y;
      acc[4 * q + 2] += c0 * va.z;
      acc[4 * q + 3] += c0 * va.w;
      float4 vb = uh[4 + q];
      acc[16 + 4 * q + 0] += c1 * vb.x;
      acc[16 + 4 * q + 1] += c1 * vb.y;
      acc[16 + 4 * q + 2] += c1 * vb.z;
      acc[16 + 4 * q + 3] += c1 * vb.w;
    }
  }
#pragma unroll
  for (int j = 0; j < 32; ++j) {
    acc[j] += __shfl_down(acc[j], 32);
    acc[j] += __shfl_down(acc[j], 16);
    acc[j] += __shfl_down(acc[j], 8);
    acc[j] += __shfl_down(acc[j], 4);
    acc[j] += __shfl_down(acc[j], 2);
    acc[j] += __shfl_down(acc[j], 1);
  }
  __shared__ float red[4][32];
  int wave = t >> 6, lane = t & 63;
  if (lane == 0) {
#pragma unroll
    for (int j = 0; j < 32; ++j) red[wave][j] = acc[j];
  }
  __syncthreads();
  if (t < 32) {
    float s = red[0][t] + red[1][t] + red[2][t] + red[3][t];
    sj_part[((size_t)b * 8 + seg) * 32 + t] = s;
  }
}

// ---------------------------------------------------------------- routing: finalize v
__global__ __launch_bounds__(256) void route_fin_k(const float* __restrict__ sj_part,
                                                   float* __restrict__ v,
                                                   float* __restrict__ out, int final_it) {
  int idx = blockIdx.x * 256 + threadIdx.x;
  if (idx >= BSZ * 32) return;
  int b = idx >> 5, j = idx & 31;
  float s = 0.f;
#pragma unroll
  for (int seg = 0; seg < 8; ++seg) s += sj_part[((size_t)b * 8 + seg) * 32 + j];
  float sn = s * s;
  float vv = sn * s / ((1.f + sn) * sqrtf(sn + 1e-8f));
  v[idx] = vv;
  if (final_it) out[idx] = fabsf(vv);
}

// ---------------------------------------------------------------- routing: b_ij update
__global__ __launch_bounds__(256) void route_upd_k(const float* __restrict__ u_hat,
                                                   const float* __restrict__ v,
                                                   float* __restrict__ b_ij, int first) {
  int i = blockIdx.x * 256 + threadIdx.x;  // 25088
  int b = blockIdx.y;
  const float4* uh = (const float4*)(u_hat + ((size_t)b * 25088 + i) * 32);
  const float4* vp = (const float4*)(v + b * 32);
  float e0 = 0.f, e1 = 0.f;
#pragma unroll
  for (int q = 0; q < 4; ++q) {
    float4 a = uh[q], wv = vp[q];
    e0 += a.x * wv.x + a.y * wv.y + a.z * wv.z + a.w * wv.w;
    float4 a2 = uh[4 + q], w2 = vp[4 + q];
    e1 += a2.x * w2.x + a2.y * w2.y + a2.z * w2.z + a2.w * w2.w;
  }
  size_t o = ((size_t)b * 25088 + i) * 2;
  if (first) {
    b_ij[o + 0] = e0;
    b_ij[o + 1] = e1;
  } else {
    b_ij[o + 0] += e0;
    b_ij[o + 1] += e1;
  }
}

// ================================================================ launch
extern "C" void kernel_launch(void* const* d_in, const int* in_sizes, int n_in,
                              void* d_out, int out_size, void* d_ws, size_t ws_size,
                              hipStream_t stream) {
  (void)in_sizes; (void)n_in; (void)out_size;
  const float* x    = (const float*)d_in[0];
  const float* w_t1 = (const float*)d_in[1];
  const float* b_t1 = (const float*)d_in[2];
  const float* w_t2 = (const float*)d_in[3];
  const float* b_t2 = (const float*)d_in[4];
  const float* w_t3 = (const float*)d_in[5];
  const float* b_t3 = (const float*)d_in[6];
  const float* w_s1 = (const float*)d_in[7];
  const float* b_s1 = (const float*)d_in[8];
  const float* w_s2 = (const float*)d_in[9];
  const float* b_s2 = (const float*)d_in[10];
  const float* w_s3 = (const float*)d_in[11];
  const float* b_s3 = (const float*)d_in[12];
  const float* w_f  = (const float*)d_in[13];
  const float* b_f  = (const float*)d_in[14];
  const float* w_p  = (const float*)d_in[15];
  const float* b_p  = (const float*)d_in[16];
  const float* w_r  = (const float*)d_in[17];
  float* out = (float*)d_out;

  char* ws = (char*)d_ws;
  if (ws_size < 238854144ull) return;
  // region 0: fused / uhat
  float* fused = (float*)(ws + 0);
  float* uhat  = (float*)(ws + 0);
  // region 1 (134,217,728): s2q -> praw/u/b_ij
  float* s2q   = (float*)(ws + 134217728);
  float* praw  = (float*)(ws + 134217728);
  float* u     = (float*)(ws + 159907840);
  float* b_ij  = (float*)(ws + 185597952);
  // region 2 (201,326,592): s1 -> t1/t2/t3/wTh/wTl
  float* s1    = (float*)(ws + 201326592);
  float* t1    = (float*)(ws + 201326592);
  float* t2    = (float*)(ws + 201850880);
  float* t3    = (float*)(ws + 202899456);
  u16*   wTh   = (u16*)  (ws + 204996608);
  u16*   wTl   = (u16*)  (ws + 215613440);
  // tail (234,881,024): persistent small tables
  u16*   w3a_h = (u16*)  (ws + 234881024);
  u16*   w3a_l = (u16*)  (ws + 235028480);
  u16*   w3b_h = (u16*)  (ws + 235175936);
  u16*   w3b_l = (u16*)  (ws + 235765760);
  float* wfT   = (float*)(ws + 236355584);
  float* sjp   = (float*)(ws + 236621824);
  float* vbuf  = (float*)(ws + 236654592);

  // small weight tables (tail region -- never clobbered)
  transpose_w3_k<128, 2><<<18, 256, 0, stream>>>(w_s2, w3a_h, w3a_l);
  transpose_w3_k<256, 4><<<36, 256, 0, stream>>>(w_s3, w3b_h, w3b_l);
  transpose_wf_k<<<261, 256, 0, stream>>>(w_f, wfT);

  // spectral: s1 scalar conv, then s2 MFMA conv (consumes s1)
  conv3x3_relu_k<1, 1><<<dim3(16, 4, BSZ), 256, 0, stream>>>(x, w_s1, b_s1, s1, 64);
  conv3x3_mfma_k<4, 2, 2, 128><<<dim3(16, BSZ), 512, 0, stream>>>(s1, w3a_h, w3a_l, b_s2, s2q);

  // s1 now dead: temporal branch + 9x9 weight tables move into its region
  conv1d_relu_k<<<512, 256, 0, stream>>>(x, w_t1, b_t1, t1, 64, 64);
  conv1d_relu_k<<<1024, 256, 0, stream>>>(t1, w_t2, b_t2, t2, 64, 128);
  conv1d_relu_k<<<2048, 256, 0, stream>>>(t2, w_t3, b_t3, t3, 128, 256);
  transpose_wp_k<<<648, 256, 0, stream>>>(w_p, wTh, wTl);

  // s3 MFMA conv -> fused
  conv3x3_mfma_k<2, 4, 4, 256><<<dim3(32, BSZ), 512, 0, stream>>>(s2q, w3b_h, w3b_l, b_s3, fused);

  // fusion fp32 in-place
  fuse1x1_k<<<4096, 256, 0, stream>>>(t3, wfT, b_f, fused);

  // primary capsules via MFMA fp16 2-pass, 16 waves (praw over dead s2q)
  conv9x9_mfma_k<<<dim3(7, BSZ), 1024, 0, stream>>>(fused, wTh, wTl, b_p, praw);
  squash_caps_k<<<3136, 256, 0, stream>>>(praw, u);

  // u_hat (overwrites fused region)
  uhat_k<<<dim3(98, BSZ), 256, 0, stream>>>(u, w_r, uhat);

  // dynamic routing, 3 iterations
  route_sj_k<<<dim3(BSZ, 8), 256, 0, stream>>>(uhat, b_ij, sjp, 0);
  route_fin_k<<<4, 256, 0, stream>>>(sjp, vbuf, out, 0);
  route_upd_k<<<dim3(98, BSZ), 256, 0, stream>>>(uhat, vbuf, b_ij, 1);

  route_sj_k<<<dim3(BSZ, 8), 256, 0, stream>>>(uhat, b_ij, sjp, 1);
  route_fin_k<<<4, 256, 0, stream>>>(sjp, vbuf, out, 0);
  route_upd_k<<<dim3(98, BSZ), 256, 0, stream>>>(uhat, vbuf, b_ij, 0);

  route_sj_k<<<dim3(BSZ, 8), 256, 0, stream>>>(uhat, b_ij, sjp, 2);
  route_fin_k<<<4, 256, 0, stream>>>(sjp, vbuf, out, 1);
}

// Round 16
// 1773.746 us; speedup vs baseline: 1.2445x; 1.0281x over previous
//
#include <hip/hip_runtime.h>
#include <math.h>

// STCCapsNet forward. B=32, C=1, H=W=64, HP=WP=28, IN_CAPS=25088, OUT 32x2x16.
// Round 16: conv3x3 MFMA kernels ported to the r12 structure -- B operand loaded
// global->registers (tables L2-resident), no lds_b, no per-tap barrier; per chunk:
// stage Ah -> 9 taps x {Ah*Bh + Ah*Bl}, stage Al -> 9 taps x {Al*Bh}. Exact bf16
// hi/lo numerics preserved. conv9x9 = r15 (fp16 2-pass, 1024 thr) unchanged.

#define BSZ 32

typedef unsigned short u16;
using bf16x8 = __attribute__((ext_vector_type(8))) short;
using f16x8 = __attribute__((ext_vector_type(8))) _Float16;
using f32x4 = __attribute__((ext_vector_type(4))) float;

__device__ inline u16 f2bf(float f) {
  union { float f; unsigned u; } v; v.f = f;
  unsigned r = v.u + 0x7FFF + ((v.u >> 16) & 1);
  return (u16)(r >> 16);
}
__device__ inline float bf2f(u16 h) {
  union { unsigned u; float f; } v; v.u = ((unsigned)h) << 16;
  return v.f;
}
__device__ inline u16 f2h(float f) {
  union { _Float16 h; u16 u; } v; v.h = (_Float16)f;
  return v.u;
}
__device__ inline float h2f(u16 b) {
  union { u16 u; _Float16 h; } v; v.u = b;
  return (float)v.h;
}

// ---------------------------------------------------------------- conv1d k=5 pad=2 + relu
__global__ __launch_bounds__(256) void conv1d_relu_k(
    const float* __restrict__ in, const float* __restrict__ w,
    const float* __restrict__ bias, float* __restrict__ out, int CI, int CO) {
  int idx = blockIdx.x * 256 + threadIdx.x;
  int total = BSZ * CO * 64;
  if (idx >= total) return;
  int x = idx & 63;
  int co = (idx >> 6) % CO;
  int b = idx / (64 * CO);
  const float* ip = in + (size_t)b * CI * 64;
  const float* wp = w + (size_t)co * CI * 5;
  float acc = bias[co];
  for (int ci = 0; ci < CI; ++ci) {
    const float* ir = ip + ci * 64;
    const float* wr_ = wp + ci * 5;
#pragma unroll
    for (int k = 0; k < 5; ++k) {
      int xx = x + k - 2;
      if (xx >= 0 && xx < 64) acc += ir[xx] * wr_[k];
    }
  }
  out[idx] = fmaxf(acc, 0.f);
}

// ---------------------------------------------------------------- conv2d 3x3 pad=1 + relu (scalar; s1 only)
template <int CI, int CIC>
__global__ __launch_bounds__(256) void conv3x3_relu_k(
    const float* __restrict__ in, const float* __restrict__ w,
    const float* __restrict__ bias, float* __restrict__ out, int CO) {
  __shared__ float in_t[CIC][18][20];
  __shared__ float w_t[CIC][16][12];
  int t = threadIdx.x;
  int co_l = t & 15;
  int g = t >> 4;
  int gy = g >> 2, gx = g & 3;
  int y0 = (blockIdx.x >> 2) * 16, x0 = (blockIdx.x & 3) * 16;
  int co = blockIdx.y * 16 + co_l;
  int b = blockIdx.z;
  float acc[16];
#pragma unroll
  for (int i = 0; i < 16; ++i) acc[i] = 0.f;

  for (int cib = 0; cib < CI / CIC; ++cib) {
    int ci0 = cib * CIC;
    for (int s = t; s < CIC * 324; s += 256) {
      int ci = s / 324;
      int r = s - ci * 324;
      int iy = r / 18, ix = r - iy * 18;
      int gyy = y0 + iy - 1, gxx = x0 + ix - 1;
      float v = 0.f;
      if (gyy >= 0 && gyy < 64 && gxx >= 0 && gxx < 64)
        v = in[((size_t)b * CI + ci0 + ci) * 4096 + gyy * 64 + gxx];
      in_t[ci][iy][ix] = v;
    }
    for (int s = t; s < CIC * 144; s += 256) {
      int ci = s / 144;
      int r = s - ci * 144;
      int cw = r / 9, k = r - cw * 9;
      w_t[ci][cw][k] = w[((size_t)(blockIdx.y * 16 + cw) * CI + ci0 + ci) * 9 + k];
    }
    __syncthreads();
    for (int ci = 0; ci < CIC; ++ci) {
      float wv[9];
#pragma unroll
      for (int k = 0; k < 9; ++k) wv[k] = w_t[ci][co_l][k];
      float pin[36];
#pragma unroll
      for (int r6 = 0; r6 < 6; ++r6)
#pragma unroll
        for (int c6 = 0; c6 < 6; ++c6)
          pin[r6 * 6 + c6] = in_t[ci][4 * gy + r6][4 * gx + c6];
#pragma unroll
      for (int py = 0; py < 4; ++py)
#pragma unroll
        for (int px = 0; px < 4; ++px) {
          float s_ = acc[py * 4 + px];
#pragma unroll
          for (int ky = 0; ky < 3; ++ky)
#pragma unroll
            for (int kx = 0; kx < 3; ++kx)
              s_ += pin[(py + ky) * 6 + (px + kx)] * wv[ky * 3 + kx];
          acc[py * 4 + px] = s_;
        }
    }
    __syncthreads();
  }
  float bv = bias[co];
#pragma unroll
  for (int py = 0; py < 4; ++py)
#pragma unroll
    for (int px = 0; px < 4; ++px)
      out[((size_t)b * CO + co) * 4096 + (size_t)(y0 + 4 * gy + py) * 64 +
          (x0 + 4 * gx + px)] = fmaxf(acc[py * 4 + px] + bv, 0.f);
}

// ---------------------------------------------------------------- w_f transpose (256,260)->(260,256)
__global__ __launch_bounds__(256) void transpose_wf_k(const float* __restrict__ wf,
                                                      float* __restrict__ wfT) {
  int idx = blockIdx.x * 256 + threadIdx.x;
  if (idx >= 256 * 260) return;
  int co = idx / 260, c = idx - co * 260;
  wfT[c * 256 + co] = wf[idx];
}

// ---------------------------------------------------------------- w_p -> fp16 WT_hi/WT_lo [g*81+tap][co][ci%32]
__global__ __launch_bounds__(256) void transpose_wp_k(const float* __restrict__ wp,
                                                      u16* __restrict__ wth,
                                                      u16* __restrict__ wtl) {
  int s = blockIdx.x;  // 0..647 = g*81 + tap
  int g = s / 81, t = s - g * 81;
  int co = threadIdx.x;
  u16 th[32], tl[32];
#pragma unroll
  for (int c = 0; c < 32; ++c) {
    float f = wp[((size_t)co * 256 + g * 32 + c) * 81 + t];
    u16 h = f2h(f);
    th[c] = h;
    tl[c] = f2h(f - h2f(h));
  }
  ushort4* dh = (ushort4*)(wth + ((size_t)s * 256 + co) * 32);
  ushort4* dl = (ushort4*)(wtl + ((size_t)s * 256 + co) * 32);
#pragma unroll
  for (int q = 0; q < 8; ++q) {
    dh[q] = make_ushort4(th[4 * q], th[4 * q + 1], th[4 * q + 2], th[4 * q + 3]);
    dl[q] = make_ushort4(tl[4 * q], tl[4 * q + 1], tl[4 * q + 2], tl[4 * q + 3]);
  }
}

// ---------------------------------------------------------------- w3 (CO,CI,3,3) -> bf16 [g*9+tap][co][32] hi/lo
template <int CO, int NCHUNK>
__global__ __launch_bounds__(256) void transpose_w3_k(const float* __restrict__ w,
                                                      u16* __restrict__ wh,
                                                      u16* __restrict__ wl) {
  int tab = blockIdx.x;  // NCHUNK*9
  int g = tab / 9, tap = tab - g * 9;
  int co = threadIdx.x;
  if (co >= CO) return;
  constexpr int CI = NCHUNK * 32;
  u16 th[32], tl[32];
#pragma unroll
  for (int c = 0; c < 32; ++c) {
    float f = w[((size_t)co * CI + g * 32 + c) * 9 + tap];
    u16 h = f2bf(f);
    th[c] = h;
    tl[c] = f2bf(f - bf2f(h));
  }
  ushort4* dh = (ushort4*)(wh + ((size_t)tab * CO + co) * 32);
  ushort4* dl = (ushort4*)(wl + ((size_t)tab * CO + co) * 32);
#pragma unroll
  for (int q = 0; q < 8; ++q) {
    dh[q] = make_ushort4(th[4 * q], th[4 * q + 1], th[4 * q + 2], th[4 * q + 3]);
    dl[q] = make_ushort4(tl[4 * q], tl[4 * q + 1], tl[4 * q + 2], tl[4 * q + 3]);
  }
}

// ---------------------------------------------------------------- conv3x3 pad=1 s=1, MFMA bf16 hi/lo, B->regs
// 512 thr = 8 waves (WMG x WNG groups), wave = 4 mb x 4 nbi. A in LDS (dense rows,
// 80B px pitch). B global->regs per tap (tables L2-resident). No per-tap barrier.
// Per chunk g: stage Ah -> 9 taps x {Ah*Bh + Ah*Bl}; stage Al -> 9 taps x {Al*Bh}.
template <int WMG, int WNG, int NCHUNK, int CO>
__global__ __launch_bounds__(512) void conv3x3_mfma_k(const float* __restrict__ in,
                                                      const u16* __restrict__ Wh,
                                                      const u16* __restrict__ Wl,
                                                      const float* __restrict__ bias,
                                                      float* __restrict__ out) {
  constexpr int CI = NCHUNK * 32;
  constexpr int ROWS = WMG + 2;
  __shared__ __align__(16) char lds_a[ROWS * 66 * 80];
  const int tid = threadIdx.x;
  const int b = blockIdx.y;
  const int y0 = blockIdx.x * WMG;  // output row base (rows of 64 px)
  const int w = tid >> 6, l = tid & 63;
  const int wm = w / WNG, wn = w % WNG;
  const int kb = l >> 4, il = l & 15;

  int abase[4];
#pragma unroll
  for (int mb = 0; mb < 4; ++mb) {
    int lp = (wm * 4 + mb) * 16 + il;
    int ly = lp >> 6, lx = lp & 63;
    abase[mb] = (ly * 66 + lx) * 80 + kb * 16;
  }
  int boff[4];  // byte offset within a tap's CO*64-byte weight block
#pragma unroll
  for (int nbi = 0; nbi < 4; ++nbi)
    boff[nbi] = ((wn * 4 + nbi) * 16 + il) * 64 + kb * 16;

  f32x4 acc[4][4];
#pragma unroll
  for (int mb = 0; mb < 4; ++mb)
#pragma unroll
    for (int nbi = 0; nbi < 4; ++nbi) {
      f32x4 z = {0.f, 0.f, 0.f, 0.f};
      acc[mb][nbi] = z;
    }

  const float* Fb = in + (size_t)b * CI * 4096;
  const char* WhB = (const char*)Wh;
  const char* WlB = (const char*)Wl;

  auto stageA = [&](int g, int plane) {
    const float* src = Fb + (size_t)g * 32 * 4096;
    for (int s = tid; s < ROWS * 66 * 8; s += 512) {
      int ciq = s & 7;
      int rest = s >> 3;
      int r = rest / 66, x = rest - r * 66;
      int row = y0 - 1 + r, col = x - 1;
      float a0 = 0.f, a1 = 0.f, a2 = 0.f, a3 = 0.f;
      if (row >= 0 && row < 64 && col >= 0 && col < 64) {
        const float* p = src + (size_t)(ciq * 4) * 4096 + row * 64 + col;
        a0 = p[0];
        a1 = p[4096];
        a2 = p[8192];
        a3 = p[12288];
      }
      u16 e0, e1, e2, e3;
      if (plane == 0) {
        e0 = f2bf(a0); e1 = f2bf(a1); e2 = f2bf(a2); e3 = f2bf(a3);
      } else {
        u16 h0 = f2bf(a0), h1 = f2bf(a1), h2 = f2bf(a2), h3 = f2bf(a3);
        e0 = f2bf(a0 - bf2f(h0)); e1 = f2bf(a1 - bf2f(h1));
        e2 = f2bf(a2 - bf2f(h2)); e3 = f2bf(a3 - bf2f(h3));
      }
      *(ushort4*)(lds_a + (r * 66 + x) * 80 + ciq * 8) = make_ushort4(e0, e1, e2, e3);
    }
  };

  for (int g = 0; g < NCHUNK; ++g) {
    // ---- phase 0: Ah x Bh + Ah x Bl ----
    __syncthreads();
    stageA(g, 0);
    __syncthreads();
#pragma unroll
    for (int tap = 0; tap < 9; ++tap) {
      const char* pb = WhB + (size_t)(g * 9 + tap) * (CO * 64);
      const char* pl = WlB + (size_t)(g * 9 + tap) * (CO * 64);
      bf16x8 bh[4], bl[4];
#pragma unroll
      for (int nbi = 0; nbi < 4; ++nbi) {
        bh[nbi] = *(const bf16x8*)(pb + boff[nbi]);
        bl[nbi] = *(const bf16x8*)(pl + boff[nbi]);
      }
      int ky = tap / 3, kx = tap - ky * 3;
      int toff = (ky * 66 + kx) * 80;
      bf16x8 av[4];
#pragma unroll
      for (int mb = 0; mb < 4; ++mb)
        av[mb] = *(const bf16x8*)(lds_a + abase[mb] + toff);
#pragma unroll
      for (int mb = 0; mb < 4; ++mb)
#pragma unroll
        for (int nbi = 0; nbi < 4; ++nbi) {
          acc[mb][nbi] = __builtin_amdgcn_mfma_f32_16x16x32_bf16(
              av[mb], bh[nbi], acc[mb][nbi], 0, 0, 0);
          acc[mb][nbi] = __builtin_amdgcn_mfma_f32_16x16x32_bf16(
              av[mb], bl[nbi], acc[mb][nbi], 0, 0, 0);
        }
    }
    // ---- phase 1: Al x Bh ----
    __syncthreads();
    stageA(g, 1);
    __syncthreads();
#pragma unroll
    for (int tap = 0; tap < 9; ++tap) {
      const char* pb = WhB + (size_t)(g * 9 + tap) * (CO * 64);
      bf16x8 bh[4];
#pragma unroll
      for (int nbi = 0; nbi < 4; ++nbi)
        bh[nbi] = *(const bf16x8*)(pb + boff[nbi]);
      int ky = tap / 3, kx = tap - ky * 3;
      int toff = (ky * 66 + kx) * 80;
      bf16x8 av[4];
#pragma unroll
      for (int mb = 0; mb < 4; ++mb)
        av[mb] = *(const bf16x8*)(lds_a + abase[mb] + toff);
#pragma unroll
      for (int mb = 0; mb < 4; ++mb)
#pragma unroll
        for (int nbi = 0; nbi < 4; ++nbi)
          acc[mb][nbi] = __builtin_amdgcn_mfma_f32_16x16x32_bf16(
              av[mb], bh[nbi], acc[mb][nbi], 0, 0, 0);
    }
  }

  const int p0 = y0 * 64;
#pragma unroll
  for (int mb = 0; mb < 4; ++mb) {
    int pixb = p0 + (wm * 4 + mb) * 16 + kb * 4;
#pragma unroll
    for (int nbi = 0; nbi < 4; ++nbi) {
      int co = (wn * 4 + nbi) * 16 + il;
      float bv_ = bias[co];
      f32x4 a = acc[mb][nbi];
      float4 o = make_float4(fmaxf(a[0] + bv_, 0.f), fmaxf(a[1] + bv_, 0.f),
                             fmaxf(a[2] + bv_, 0.f), fmaxf(a[3] + bv_, 0.f));
      *(float4*)(out + (size_t)(b * CO + co) * 4096 + pixb) = o;
    }
  }
}

// ---------------------------------------------------------------- 1x1 fusion conv, fp32 IN-PLACE
__global__ __launch_bounds__(256) void fuse1x1_k(const float* __restrict__ t3,
                                                 const float* __restrict__ wfT,
                                                 const float* __restrict__ bf,
                                                 float* __restrict__ a) {
  __shared__ float in_t[260][32];
  int t = threadIdx.x;
  int b = blockIdx.x >> 7;
  int p0 = (blockIdx.x & 127) * 32;
  for (int s = t; s < 260 * 32; s += 256) {
    int c = s >> 5, pp = s & 31;
    float v;
    if (c < 4)
      v = t3[(size_t)b * 16384 + c * 4096 + p0 + pp];
    else
      v = a[((size_t)b * 256 + (c - 4)) * 4096 + p0 + pp];
    in_t[c][pp] = v;
  }
  __syncthreads();
  int co = t;
  float acc[32];
#pragma unroll
  for (int pp = 0; pp < 32; ++pp) acc[pp] = 0.f;
  for (int c = 0; c < 260; ++c) {
    float wv = wfT[c * 256 + co];
#pragma unroll
    for (int pp = 0; pp < 32; ++pp) acc[pp] += wv * in_t[c][pp];
  }
  float bv = bf[co];
#pragma unroll
  for (int pp = 0; pp < 32; ++pp)
    a[((size_t)b * 256 + co) * 4096 + p0 + pp] = acc[pp] + bv;
}

// ---------------------------------------------------------------- 9x9 s2 conv, MFMA fp16 2-pass, 16 waves
// (round-15 version, unchanged)
__global__ __launch_bounds__(1024) void conv9x9_mfma_k(const float* __restrict__ fused,
                                                       const u16* __restrict__ WTh,
                                                       const u16* __restrict__ WTl,
                                                       const float* __restrict__ bias,
                                                       float* __restrict__ praw) {
  constexpr int APLANE = 19 * 32 * 80;  // 48640 B per parity half-plane
  __shared__ __align__(16) char lds_a[2 * APLANE];   // 97280
  const int tid = threadIdx.x;
  const int b = blockIdx.y, tile = blockIdx.x;
  const int p0 = tile * 128;
  const int oy0 = p0 / 28;
  const int w = tid >> 6, l = tid & 63;
  const int wm = w >> 3, wn = w & 7;
  const int kb = l >> 4, il = l & 15;

  int abase[4];
#pragma unroll
  for (int mb = 0; mb < 4; ++mb) {
    int p = p0 + (wm * 4 + mb) * 16 + il;
    int oy = p / 28, ox = p - oy * 28;
    abase[mb] = (2 * (oy - oy0)) * 2560 + ox * 80 + kb * 16;
  }
  int boff[2];
#pragma unroll
  for (int nbi = 0; nbi < 2; ++nbi)
    boff[nbi] = (wn * 32 + nbi * 16 + il) * 64 + kb * 16;

  f32x4 acc[4][2];
#pragma unroll
  for (int mb = 0; mb < 4; ++mb)
#pragma unroll
    for (int nbi = 0; nbi < 2; ++nbi) {
      f32x4 z = {0.f, 0.f, 0.f, 0.f};
      acc[mb][nbi] = z;
    }

  const float* Fb = fused + (size_t)b * 256 * 4096;
  const char* WhB = (const char*)WTh;
  const char* WlB = (const char*)WTl;

  auto stageA = [&](int g) {
    const float* src = Fb + (size_t)g * 32 * 4096;
    for (int s = tid; s < 19 * 63 * 8; s += 1024) {
      int ciq = s / 1197;
      int rem = s - ciq * 1197;
      int r = rem / 63, t63 = rem - r * 63;
      int x2 = (t63 < 32) ? 2 * t63 : 2 * (t63 - 32) + 1;
      int iy = 2 * oy0 + r;
      float a0 = 0.f, a1 = 0.f, a2 = 0.f, a3 = 0.f;
      if (iy < 64) {
        const float* pp0 = src + (size_t)(ciq * 4) * 4096 + iy * 64 + x2;
        a0 = pp0[0];
        a1 = pp0[4096];
        a2 = pp0[8192];
        a3 = pp0[12288];
      }
      u16 e0 = f2h(a0), e1 = f2h(a1), e2 = f2h(a2), e3 = f2h(a3);
      int off = (x2 & 1) * APLANE + (r * 32 + (x2 >> 1)) * 80 + ciq * 8;
      *(ushort4*)(lds_a + off) = make_ushort4(e0, e1, e2, e3);
    }
  };

  for (int g = 0; g < 8; ++g) {
    __syncthreads();
    stageA(g);
    __syncthreads();
#pragma unroll 3
    for (int t = 0; t < 81; ++t) {
      const char* pb = WhB + (size_t)(g * 81 + t) * 16384;
      const char* pl = WlB + (size_t)(g * 81 + t) * 16384;
      f16x8 bh[2], bl[2];
#pragma unroll
      for (int nbi = 0; nbi < 2; ++nbi) {
        bh[nbi] = *(const f16x8*)(pb + boff[nbi]);
        bl[nbi] = *(const f16x8*)(pl + boff[nbi]);
      }
      int ky = t / 9, kx = t - ky * 9;
      int toff = (kx & 1) * APLANE + ky * 2560 + (kx >> 1) * 80;
      f16x8 av[4];
#pragma unroll
      for (int mb = 0; mb < 4; ++mb)
        av[mb] = *(const f16x8*)(lds_a + abase[mb] + toff);
#pragma unroll
      for (int mb = 0; mb < 4; ++mb)
#pragma unroll
        for (int nbi = 0; nbi < 2; ++nbi) {
          acc[mb][nbi] = __builtin_amdgcn_mfma_f32_16x16x32_f16(
              av[mb], bh[nbi], acc[mb][nbi], 0, 0, 0);
          acc[mb][nbi] = __builtin_amdgcn_mfma_f32_16x16x32_f16(
              av[mb], bl[nbi], acc[mb][nbi], 0, 0, 0);
        }
    }
  }

#pragma unroll
  for (int mb = 0; mb < 4; ++mb) {
    int pixb = p0 + (wm * 4 + mb) * 16 + kb * 4;
    if (pixb < 784) {
#pragma unroll
      for (int nbi = 0; nbi < 2; ++nbi) {
        int co = wn * 32 + nbi * 16 + il;
        float bv_ = bias[co];
        f32x4 a = acc[mb][nbi];
        float4 o = make_float4(a[0] + bv_, a[1] + bv_, a[2] + bv_, a[3] + bv_);
        *(float4*)(praw + (size_t)(b * 256 + co) * 784 + pixb) = o;
      }
    }
  }
}

// ---------------------------------------------------------------- capsule squash: p(B,256,784) -> u(B,25088,8)
__global__ __launch_bounds__(256) void squash_caps_k(const float* __restrict__ p,
                                                     float* __restrict__ u) {
  int idx = blockIdx.x * 256 + threadIdx.x;
  if (idx >= BSZ * 25088) return;
  int b = idx / 25088;
  int cap = idx - b * 25088;
  int prim = cap / 784, pix = cap - prim * 784;
  const float* pp = p + ((size_t)b * 256 + prim * 8) * 784 + pix;
  float x[8];
  float sn = 0.f;
#pragma unroll
  for (int d = 0; d < 8; ++d) {
    x[d] = pp[(size_t)d * 784];
    sn += x[d] * x[d];
  }
  float scale = sn / ((1.f + sn) * sqrtf(sn + 1e-8f));
  float4 r0 = {x[0] * scale, x[1] * scale, x[2] * scale, x[3] * scale};
  float4 r1 = {x[4] * scale, x[5] * scale, x[6] * scale, x[7] * scale};
  float4* dst = (float4*)(u + (size_t)idx * 8);
  dst[0] = r0;
  dst[1] = r1;
}

// ---------------------------------------------------------------- u_hat = einsum('iodk,bik->biod')
__global__ __launch_bounds__(256) void uhat_k(const float* __restrict__ u,
                                              const float* __restrict__ w_r,
                                              float* __restrict__ u_hat) {
  int i = blockIdx.x * 256 + threadIdx.x;  // 25088
  int b = blockIdx.y;
  const float4* up = (const float4*)(u + ((size_t)b * 25088 + i) * 8);
  float4 ua = up[0], ub = up[1];
  const float4* wr = (const float4*)(w_r + (size_t)i * 256);
  float res[32];
#pragma unroll
  for (int od = 0; od < 32; ++od) {
    float4 wa = wr[od * 2], wb = wr[od * 2 + 1];
    res[od] = wa.x * ua.x + wa.y * ua.y + wa.z * ua.z + wa.w * ua.w +
              wb.x * ub.x + wb.y * ub.y + wb.z * ub.z + wb.w * ub.w;
  }
  float4* dst = (float4*)(u_hat + ((size_t)b * 25088 + i) * 32);
#pragma unroll
  for (int q = 0; q < 8; ++q)
    dst[q] = make_float4(res[4 * q], res[4 * q + 1], res[4 * q + 2], res[4 * q + 3]);
}

// ---------------------------------------------------------------- routing: partial s_j per (b,seg)
__global__ __launch_bounds__(256) void route_sj_k(const float* __restrict__ u_hat,
                                                  const float* __restrict__ b_ij,
                                                  float* __restrict__ sj_part, int iter) {
  int b = blockIdx.x;
  int seg = blockIdx.y;
  int t = threadIdx.x;
  float acc[32];
#pragma unroll
  for (int j = 0; j < 32; ++j) acc[j] = 0.f;
  int i0 = seg * 3136;
  for (int i = i0 + t; i < i0 + 3136; i += 256) {
    float c0 = 0.5f, c1 = 0.5f;
    if (iter > 0) {
      float b0 = b_ij[((size_t)b * 25088 + i) * 2 + 0];
      float b1 = b_ij[((size_t)b * 25088 + i) * 2 + 1];
      float m = fmaxf(b0, b1);
      float e0 = expf(b0 - m), e1 = expf(b1 - m);
      float inv = 1.f / (e0 + e1);
      c0 = e0 * inv;
      c1 = e1 * inv;
    }
    const float4* uh = (const float4*)(u_hat + ((size_t)b * 25088 + i) * 32);
#pragma unroll
    for (int q = 0; q < 4; ++q) {
      float4 va = uh[q];
      acc[4 * q + 0] += c0 * va.x;
      acc[4 * q + 1] += c0 * va.y;
      acc[4 * q + 2] += c0 * va.z;
      acc[4 * q + 3] += c0 * va.w;
      float4 vb = uh[4 + q];
      acc[16 + 4 * q + 0] += c1 * vb.x;
      acc[16 + 4 * q + 1] += c1 * vb.y;
      acc[16 + 4 * q + 2] += c1 * vb.z;
      acc[16 + 4 * q + 3] += c1 * vb.w;
    }
  }
#pragma unroll
  for (int j = 0; j < 32; ++j) {
    acc[j] += __shfl_down(acc[j], 32);
    acc[j] += __shfl_down(acc[j], 16);
    acc[j] += __shfl_down(acc[j], 8);
    acc[j] += __shfl_down(acc[j], 4);
    acc[j] += __shfl_down(acc[j], 2);
    acc[j] += __shfl_down(acc[j], 1);
  }
  __shared__ float red[4][32];
  int wave = t >> 6, lane = t & 63;
  if (lane == 0) {
#pragma unroll
    for (int j = 0; j < 32; ++j) red[wave][j] = acc[j];
  }
  __syncthreads();
  if (t < 32) {
    float s = red[0][t] + red[1][t] + red[2][t] + red[3][t];
    sj_part[((size_t)b * 8 + seg) * 32 + t] = s;
  }
}

// ---------------------------------------------------------------- routing: finalize v
__global__ __launch_bounds__(256) void route_fin_k(const float* __restrict__ sj_part,
                                                   float* __restrict__ v,
                                                   float* __restrict__ out, int final_it) {
  int idx = blockIdx.x * 256 + threadIdx.x;
  if (idx >= BSZ * 32) return;
  int b = idx >> 5, j = idx & 31;
  float s = 0.f;
#pragma unroll
  for (int seg = 0; seg < 8; ++seg) s += sj_part[((size_t)b * 8 + seg) * 32 + j];
  float sn = s * s;
  float vv = sn * s / ((1.f + sn) * sqrtf(sn + 1e-8f));
  v[idx] = vv;
  if (final_it) out[idx] = fabsf(vv);
}

// ---------------------------------------------------------------- routing: b_ij update
__global__ __launch_bounds__(256) void route_upd_k(const float* __restrict__ u_hat,
                                                   const float* __restrict__ v,
                                                   float* __restrict__ b_ij, int first) {
  int i = blockIdx.x * 256 + threadIdx.x;  // 25088
  int b = blockIdx.y;
  const float4* uh = (const float4*)(u_hat + ((size_t)b * 25088 + i) * 32);
  const float4* vp = (const float4*)(v + b * 32);
  float e0 = 0.f, e1 = 0.f;
#pragma unroll
  for (int q = 0; q < 4; ++q) {
    float4 a = uh[q], wv = vp[q];
    e0 += a.x * wv.x + a.y * wv.y + a.z * wv.z + a.w * wv.w;
    float4 a2 = uh[4 + q], w2 = vp[4 + q];
    e1 += a2.x * w2.x + a2.y * w2.y + a2.z * w2.z + a2.w * w2.w;
  }
  size_t o = ((size_t)b * 25088 + i) * 2;
  if (first) {
    b_ij[o + 0] = e0;
    b_ij[o + 1] = e1;
  } else {
    b_ij[o + 0] += e0;
    b_ij[o + 1] += e1;
  }
}

// ================================================================ launch
extern "C" void kernel_launch(void* const* d_in, const int* in_sizes, int n_in,
                              void* d_out, int out_size, void* d_ws, size_t ws_size,
                              hipStream_t stream) {
  (void)in_sizes; (void)n_in; (void)out_size;
  const float* x    = (const float*)d_in[0];
  const float* w_t1 = (const float*)d_in[1];
  const float* b_t1 = (const float*)d_in[2];
  const float* w_t2 = (const float*)d_in[3];
  const float* b_t2 = (const float*)d_in[4];
  const float* w_t3 = (const float*)d_in[5];
  const float* b_t3 = (const float*)d_in[6];
  const float* w_s1 = (const float*)d_in[7];
  const float* b_s1 = (const float*)d_in[8];
  const float* w_s2 = (const float*)d_in[9];
  const float* b_s2 = (const float*)d_in[10];
  const float* w_s3 = (const float*)d_in[11];
  const float* b_s3 = (const float*)d_in[12];
  const float* w_f  = (const float*)d_in[13];
  const float* b_f  = (const float*)d_in[14];
  const float* w_p  = (const float*)d_in[15];
  const float* b_p  = (const float*)d_in[16];
  const float* w_r  = (const float*)d_in[17];
  float* out = (float*)d_out;

  char* ws = (char*)d_ws;
  if (ws_size < 238854144ull) return;
  // region 0: fused / uhat
  float* fused = (float*)(ws + 0);
  float* uhat  = (float*)(ws + 0);
  // region 1 (134,217,728): s2q -> praw/u/b_ij
  float* s2q   = (float*)(ws + 134217728);
  float* praw  = (float*)(ws + 134217728);
  float* u     = (float*)(ws + 159907840);
  float* b_ij  = (float*)(ws + 185597952);
  // region 2 (201,326,592): s1 -> t1/t2/t3/wTh/wTl
  float* s1    = (float*)(ws + 201326592);
  float* t1    = (float*)(ws + 201326592);
  float* t2    = (float*)(ws + 201850880);
  float* t3    = (float*)(ws + 202899456);
  u16*   wTh   = (u16*)  (ws + 204996608);
  u16*   wTl   = (u16*)  (ws + 215613440);
  // tail (234,881,024): persistent small tables
  u16*   w3a_h = (u16*)  (ws + 234881024);
  u16*   w3a_l = (u16*)  (ws + 235028480);
  u16*   w3b_h = (u16*)  (ws + 235175936);
  u16*   w3b_l = (u16*)  (ws + 235765760);
  float* wfT   = (float*)(ws + 236355584);
  float* sjp   = (float*)(ws + 236621824);
  float* vbuf  = (float*)(ws + 236654592);

  // small weight tables (tail region -- never clobbered)
  transpose_w3_k<128, 2><<<18, 256, 0, stream>>>(w_s2, w3a_h, w3a_l);
  transpose_w3_k<256, 4><<<36, 256, 0, stream>>>(w_s3, w3b_h, w3b_l);
  transpose_wf_k<<<261, 256, 0, stream>>>(w_f, wfT);

  // spectral: s1 scalar conv, then s2 MFMA conv (consumes s1)
  conv3x3_relu_k<1, 1><<<dim3(16, 4, BSZ), 256, 0, stream>>>(x, w_s1, b_s1, s1, 64);
  conv3x3_mfma_k<4, 2, 2, 128><<<dim3(16, BSZ), 512, 0, stream>>>(s1, w3a_h, w3a_l, b_s2, s2q);

  // s1 now dead: temporal branch + 9x9 weight tables move into its region
  conv1d_relu_k<<<512, 256, 0, stream>>>(x, w_t1, b_t1, t1, 64, 64);
  conv1d_relu_k<<<1024, 256, 0, stream>>>(t1, w_t2, b_t2, t2, 64, 128);
  conv1d_relu_k<<<2048, 256, 0, stream>>>(t2, w_t3, b_t3, t3, 128, 256);
  transpose_wp_k<<<648, 256, 0, stream>>>(w_p, wTh, wTl);

  // s3 MFMA conv -> fused
  conv3x3_mfma_k<2, 4, 4, 256><<<dim3(32, BSZ), 512, 0, stream>>>(s2q, w3b_h, w3b_l, b_s3, fused);

  // fusion fp32 in-place
  fuse1x1_k<<<4096, 256, 0, stream>>>(t3, wfT, b_f, fused);

  // primary capsules via MFMA fp16 2-pass, 16 waves (praw over dead s2q)
  conv9x9_mfma_k<<<dim3(7, BSZ), 1024, 0, stream>>>(fused, wTh, wTl, b_p, praw);
  squash_caps_k<<<3136, 256, 0, stream>>>(praw, u);

  // u_hat (overwrites fused region)
  uhat_k<<<dim3(98, BSZ), 256, 0, stream>>>(u, w_r, uhat);

  // dynamic routing, 3 iterations
  route_sj_k<<<dim3(BSZ, 8), 256, 0, stream>>>(uhat, b_ij, sjp, 0);
  route_fin_k<<<4, 256, 0, stream>>>(sjp, vbuf, out, 0);
  route_upd_k<<<dim3(98, BSZ), 256, 0, stream>>>(uhat, vbuf, b_ij, 1);

  route_sj_k<<<dim3(BSZ, 8), 256, 0, stream>>>(uhat, b_ij, sjp, 1);
  route_fin_k<<<4, 256, 0, stream>>>(sjp, vbuf, out, 0);
  route_upd_k<<<dim3(98, BSZ), 256, 0, stream>>>(uhat, vbuf, b_ij, 0);

  route_sj_k<<<dim3(BSZ, 8), 256, 0, stream>>>(uhat, b_ij, sjp, 2);
  route_fin_k<<<4, 256, 0, stream>>>(sjp, vbuf, out, 1);
}

// Round 17
// 1559.967 us; speedup vs baseline: 1.4151x; 1.1370x over previous
//
#include <hip/hip_runtime.h>
#include <math.h>

// STCCapsNet forward. B=32, C=1, H=W=64, HP=WP=28, IN_CAPS=25088, OUT 32x2x16.
// Round 17: (a) fuse1x1 -> MFMA (exact bf16 hi/lo 3-pass; K=260 padded to 288;
// A staged from t3+s3 with one global read -> hi+lo planes; in-place safe).
// (b) route_upd fused into route_sj (route_fsj_k): one u_hat read per iteration.
// conv9x9 = r15 (fp16 2-pass, 1024 thr); conv3x3 = r16 (B->regs) unchanged.

#define BSZ 32

typedef unsigned short u16;
using bf16x8 = __attribute__((ext_vector_type(8))) short;
using f16x8 = __attribute__((ext_vector_type(8))) _Float16;
using f32x4 = __attribute__((ext_vector_type(4))) float;

__device__ inline u16 f2bf(float f) {
  union { float f; unsigned u; } v; v.f = f;
  unsigned r = v.u + 0x7FFF + ((v.u >> 16) & 1);
  return (u16)(r >> 16);
}
__device__ inline float bf2f(u16 h) {
  union { unsigned u; float f; } v; v.u = ((unsigned)h) << 16;
  return v.f;
}
__device__ inline u16 f2h(float f) {
  union { _Float16 h; u16 u; } v; v.h = (_Float16)f;
  return v.u;
}
__device__ inline float h2f(u16 b) {
  union { u16 u; _Float16 h; } v; v.u = b;
  return (float)v.h;
}

// ---------------------------------------------------------------- conv1d k=5 pad=2 + relu
__global__ __launch_bounds__(256) void conv1d_relu_k(
    const float* __restrict__ in, const float* __restrict__ w,
    const float* __restrict__ bias, float* __restrict__ out, int CI, int CO) {
  int idx = blockIdx.x * 256 + threadIdx.x;
  int total = BSZ * CO * 64;
  if (idx >= total) return;
  int x = idx & 63;
  int co = (idx >> 6) % CO;
  int b = idx / (64 * CO);
  const float* ip = in + (size_t)b * CI * 64;
  const float* wp = w + (size_t)co * CI * 5;
  float acc = bias[co];
  for (int ci = 0; ci < CI; ++ci) {
    const float* ir = ip + ci * 64;
    const float* wr_ = wp + ci * 5;
#pragma unroll
    for (int k = 0; k < 5; ++k) {
      int xx = x + k - 2;
      if (xx >= 0 && xx < 64) acc += ir[xx] * wr_[k];
    }
  }
  out[idx] = fmaxf(acc, 0.f);
}

// ---------------------------------------------------------------- conv2d 3x3 pad=1 + relu (scalar; s1 only)
template <int CI, int CIC>
__global__ __launch_bounds__(256) void conv3x3_relu_k(
    const float* __restrict__ in, const float* __restrict__ w,
    const float* __restrict__ bias, float* __restrict__ out, int CO) {
  __shared__ float in_t[CIC][18][20];
  __shared__ float w_t[CIC][16][12];
  int t = threadIdx.x;
  int co_l = t & 15;
  int g = t >> 4;
  int gy = g >> 2, gx = g & 3;
  int y0 = (blockIdx.x >> 2) * 16, x0 = (blockIdx.x & 3) * 16;
  int co = blockIdx.y * 16 + co_l;
  int b = blockIdx.z;
  float acc[16];
#pragma unroll
  for (int i = 0; i < 16; ++i) acc[i] = 0.f;

  for (int cib = 0; cib < CI / CIC; ++cib) {
    int ci0 = cib * CIC;
    for (int s = t; s < CIC * 324; s += 256) {
      int ci = s / 324;
      int r = s - ci * 324;
      int iy = r / 18, ix = r - iy * 18;
      int gyy = y0 + iy - 1, gxx = x0 + ix - 1;
      float v = 0.f;
      if (gyy >= 0 && gyy < 64 && gxx >= 0 && gxx < 64)
        v = in[((size_t)b * CI + ci0 + ci) * 4096 + gyy * 64 + gxx];
      in_t[ci][iy][ix] = v;
    }
    for (int s = t; s < CIC * 144; s += 256) {
      int ci = s / 144;
      int r = s - ci * 144;
      int cw = r / 9, k = r - cw * 9;
      w_t[ci][cw][k] = w[((size_t)(blockIdx.y * 16 + cw) * CI + ci0 + ci) * 9 + k];
    }
    __syncthreads();
    for (int ci = 0; ci < CIC; ++ci) {
      float wv[9];
#pragma unroll
      for (int k = 0; k < 9; ++k) wv[k] = w_t[ci][co_l][k];
      float pin[36];
#pragma unroll
      for (int r6 = 0; r6 < 6; ++r6)
#pragma unroll
        for (int c6 = 0; c6 < 6; ++c6)
          pin[r6 * 6 + c6] = in_t[ci][4 * gy + r6][4 * gx + c6];
#pragma unroll
      for (int py = 0; py < 4; ++py)
#pragma unroll
        for (int px = 0; px < 4; ++px) {
          float s_ = acc[py * 4 + px];
#pragma unroll
          for (int ky = 0; ky < 3; ++ky)
#pragma unroll
            for (int kx = 0; kx < 3; ++kx)
              s_ += pin[(py + ky) * 6 + (px + kx)] * wv[ky * 3 + kx];
          acc[py * 4 + px] = s_;
        }
    }
    __syncthreads();
  }
  float bv = bias[co];
#pragma unroll
  for (int py = 0; py < 4; ++py)
#pragma unroll
    for (int px = 0; px < 4; ++px)
      out[((size_t)b * CO + co) * 4096 + (size_t)(y0 + 4 * gy + py) * 64 +
          (x0 + 4 * gx + px)] = fmaxf(acc[py * 4 + px] + bv, 0.f);
}

// ---------------------------------------------------------------- w_f -> bf16 [9][256][32] hi/lo (K padded 260->288)
__global__ __launch_bounds__(256) void transpose_wf1_k(const float* __restrict__ wf,
                                                       u16* __restrict__ wh,
                                                       u16* __restrict__ wl) {
  int c = blockIdx.x;  // 0..8
  int co = threadIdx.x;
  u16 th[32], tl[32];
#pragma unroll
  for (int j = 0; j < 32; ++j) {
    int lc = c * 32 + j;
    float f = (lc < 260) ? wf[(size_t)co * 260 + lc] : 0.f;
    u16 h = f2bf(f);
    th[j] = h;
    tl[j] = f2bf(f - bf2f(h));
  }
  ushort4* dh = (ushort4*)(wh + ((size_t)c * 256 + co) * 32);
  ushort4* dl = (ushort4*)(wl + ((size_t)c * 256 + co) * 32);
#pragma unroll
  for (int q = 0; q < 8; ++q) {
    dh[q] = make_ushort4(th[4 * q], th[4 * q + 1], th[4 * q + 2], th[4 * q + 3]);
    dl[q] = make_ushort4(tl[4 * q], tl[4 * q + 1], tl[4 * q + 2], tl[4 * q + 3]);
  }
}

// ---------------------------------------------------------------- w_p -> fp16 WT_hi/WT_lo [g*81+tap][co][ci%32]
__global__ __launch_bounds__(256) void transpose_wp_k(const float* __restrict__ wp,
                                                      u16* __restrict__ wth,
                                                      u16* __restrict__ wtl) {
  int s = blockIdx.x;  // 0..647 = g*81 + tap
  int g = s / 81, t = s - g * 81;
  int co = threadIdx.x;
  u16 th[32], tl[32];
#pragma unroll
  for (int c = 0; c < 32; ++c) {
    float f = wp[((size_t)co * 256 + g * 32 + c) * 81 + t];
    u16 h = f2h(f);
    th[c] = h;
    tl[c] = f2h(f - h2f(h));
  }
  ushort4* dh = (ushort4*)(wth + ((size_t)s * 256 + co) * 32);
  ushort4* dl = (ushort4*)(wtl + ((size_t)s * 256 + co) * 32);
#pragma unroll
  for (int q = 0; q < 8; ++q) {
    dh[q] = make_ushort4(th[4 * q], th[4 * q + 1], th[4 * q + 2], th[4 * q + 3]);
    dl[q] = make_ushort4(tl[4 * q], tl[4 * q + 1], tl[4 * q + 2], tl[4 * q + 3]);
  }
}

// ---------------------------------------------------------------- w3 (CO,CI,3,3) -> bf16 [g*9+tap][co][32] hi/lo
template <int CO, int NCHUNK>
__global__ __launch_bounds__(256) void transpose_w3_k(const float* __restrict__ w,
                                                      u16* __restrict__ wh,
                                                      u16* __restrict__ wl) {
  int tab = blockIdx.x;  // NCHUNK*9
  int g = tab / 9, tap = tab - g * 9;
  int co = threadIdx.x;
  if (co >= CO) return;
  constexpr int CI = NCHUNK * 32;
  u16 th[32], tl[32];
#pragma unroll
  for (int c = 0; c < 32; ++c) {
    float f = w[((size_t)co * CI + g * 32 + c) * 9 + tap];
    u16 h = f2bf(f);
    th[c] = h;
    tl[c] = f2bf(f - bf2f(h));
  }
  ushort4* dh = (ushort4*)(wh + ((size_t)tab * CO + co) * 32);
  ushort4* dl = (ushort4*)(wl + ((size_t)tab * CO + co) * 32);
#pragma unroll
  for (int q = 0; q < 8; ++q) {
    dh[q] = make_ushort4(th[4 * q], th[4 * q + 1], th[4 * q + 2], th[4 * q + 3]);
    dl[q] = make_ushort4(tl[4 * q], tl[4 * q + 1], tl[4 * q + 2], tl[4 * q + 3]);
  }
}

// ---------------------------------------------------------------- conv3x3 pad=1 s=1, MFMA bf16 hi/lo, B->regs
// (round-16 version)
template <int WMG, int WNG, int NCHUNK, int CO>
__global__ __launch_bounds__(512) void conv3x3_mfma_k(const float* __restrict__ in,
                                                      const u16* __restrict__ Wh,
                                                      const u16* __restrict__ Wl,
                                                      const float* __restrict__ bias,
                                                      float* __restrict__ out) {
  constexpr int CI = NCHUNK * 32;
  constexpr int ROWS = WMG + 2;
  __shared__ __align__(16) char lds_a[ROWS * 66 * 80];
  const int tid = threadIdx.x;
  const int b = blockIdx.y;
  const int y0 = blockIdx.x * WMG;
  const int w = tid >> 6, l = tid & 63;
  const int wm = w / WNG, wn = w % WNG;
  const int kb = l >> 4, il = l & 15;

  int abase[4];
#pragma unroll
  for (int mb = 0; mb < 4; ++mb) {
    int lp = (wm * 4 + mb) * 16 + il;
    int ly = lp >> 6, lx = lp & 63;
    abase[mb] = (ly * 66 + lx) * 80 + kb * 16;
  }
  int boff[4];
#pragma unroll
  for (int nbi = 0; nbi < 4; ++nbi)
    boff[nbi] = ((wn * 4 + nbi) * 16 + il) * 64 + kb * 16;

  f32x4 acc[4][4];
#pragma unroll
  for (int mb = 0; mb < 4; ++mb)
#pragma unroll
    for (int nbi = 0; nbi < 4; ++nbi) {
      f32x4 z = {0.f, 0.f, 0.f, 0.f};
      acc[mb][nbi] = z;
    }

  const float* Fb = in + (size_t)b * CI * 4096;
  const char* WhB = (const char*)Wh;
  const char* WlB = (const char*)Wl;

  auto stageA = [&](int g, int plane) {
    const float* src = Fb + (size_t)g * 32 * 4096;
    for (int s = tid; s < ROWS * 66 * 8; s += 512) {
      int ciq = s & 7;
      int rest = s >> 3;
      int r = rest / 66, x = rest - r * 66;
      int row = y0 - 1 + r, col = x - 1;
      float a0 = 0.f, a1 = 0.f, a2 = 0.f, a3 = 0.f;
      if (row >= 0 && row < 64 && col >= 0 && col < 64) {
        const float* p = src + (size_t)(ciq * 4) * 4096 + row * 64 + col;
        a0 = p[0];
        a1 = p[4096];
        a2 = p[8192];
        a3 = p[12288];
      }
      u16 e0, e1, e2, e3;
      if (plane == 0) {
        e0 = f2bf(a0); e1 = f2bf(a1); e2 = f2bf(a2); e3 = f2bf(a3);
      } else {
        u16 h0 = f2bf(a0), h1 = f2bf(a1), h2 = f2bf(a2), h3 = f2bf(a3);
        e0 = f2bf(a0 - bf2f(h0)); e1 = f2bf(a1 - bf2f(h1));
        e2 = f2bf(a2 - bf2f(h2)); e3 = f2bf(a3 - bf2f(h3));
      }
      *(ushort4*)(lds_a + (r * 66 + x) * 80 + ciq * 8) = make_ushort4(e0, e1, e2, e3);
    }
  };

  for (int g = 0; g < NCHUNK; ++g) {
    // ---- phase 0: Ah x Bh + Ah x Bl ----
    __syncthreads();
    stageA(g, 0);
    __syncthreads();
#pragma unroll
    for (int tap = 0; tap < 9; ++tap) {
      const char* pb = WhB + (size_t)(g * 9 + tap) * (CO * 64);
      const char* pl = WlB + (size_t)(g * 9 + tap) * (CO * 64);
      bf16x8 bh[4], bl[4];
#pragma unroll
      for (int nbi = 0; nbi < 4; ++nbi) {
        bh[nbi] = *(const bf16x8*)(pb + boff[nbi]);
        bl[nbi] = *(const bf16x8*)(pl + boff[nbi]);
      }
      int ky = tap / 3, kx = tap - ky * 3;
      int toff = (ky * 66 + kx) * 80;
      bf16x8 av[4];
#pragma unroll
      for (int mb = 0; mb < 4; ++mb)
        av[mb] = *(const bf16x8*)(lds_a + abase[mb] + toff);
#pragma unroll
      for (int mb = 0; mb < 4; ++mb)
#pragma unroll
        for (int nbi = 0; nbi < 4; ++nbi) {
          acc[mb][nbi] = __builtin_amdgcn_mfma_f32_16x16x32_bf16(
              av[mb], bh[nbi], acc[mb][nbi], 0, 0, 0);
          acc[mb][nbi] = __builtin_amdgcn_mfma_f32_16x16x32_bf16(
              av[mb], bl[nbi], acc[mb][nbi], 0, 0, 0);
        }
    }
    // ---- phase 1: Al x Bh ----
    __syncthreads();
    stageA(g, 1);
    __syncthreads();
#pragma unroll
    for (int tap = 0; tap < 9; ++tap) {
      const char* pb = WhB + (size_t)(g * 9 + tap) * (CO * 64);
      bf16x8 bh[4];
#pragma unroll
      for (int nbi = 0; nbi < 4; ++nbi)
        bh[nbi] = *(const bf16x8*)(pb + boff[nbi]);
      int ky = tap / 3, kx = tap - ky * 3;
      int toff = (ky * 66 + kx) * 80;
      bf16x8 av[4];
#pragma unroll
      for (int mb = 0; mb < 4; ++mb)
        av[mb] = *(const bf16x8*)(lds_a + abase[mb] + toff);
#pragma unroll
      for (int mb = 0; mb < 4; ++mb)
#pragma unroll
        for (int nbi = 0; nbi < 4; ++nbi)
          acc[mb][nbi] = __builtin_amdgcn_mfma_f32_16x16x32_bf16(
              av[mb], bh[nbi], acc[mb][nbi], 0, 0, 0);
    }
  }

  const int p0 = y0 * 64;
#pragma unroll
  for (int mb = 0; mb < 4; ++mb) {
    int pixb = p0 + (wm * 4 + mb) * 16 + kb * 4;
#pragma unroll
    for (int nbi = 0; nbi < 4; ++nbi) {
      int co = (wn * 4 + nbi) * 16 + il;
      float bv_ = bias[co];
      f32x4 a = acc[mb][nbi];
      float4 o = make_float4(fmaxf(a[0] + bv_, 0.f), fmaxf(a[1] + bv_, 0.f),
                             fmaxf(a[2] + bv_, 0.f), fmaxf(a[3] + bv_, 0.f));
      *(float4*)(out + (size_t)(b * CO + co) * 4096 + pixb) = o;
    }
  }
}

// ---------------------------------------------------------------- 1x1 fusion via MFMA bf16 hi/lo (exact)
// Block = 128 px x 256 co; 512 thr = 8 waves (2M x 4N), wave = 4mb x 4nbi.
// A = concat(t3[0..3], s3[0..255]) K=260 padded to 288 (9 chunks). Per chunk:
// one source read -> hi+lo LDS planes; {Ah*Bh + Ah*Bl} + {Al*Bh}. In-place on s3
// (all reads precede epilogue writes; blocks own disjoint pixels).
__global__ __launch_bounds__(512) void fuse_mfma_k(const float* __restrict__ t3,
                                                   const u16* __restrict__ Wh,
                                                   const u16* __restrict__ Wl,
                                                   const float* __restrict__ bf,
                                                   float* __restrict__ a) {
  constexpr int APL = 128 * 80;  // 10240 B per plane
  __shared__ __align__(16) char lds_a[2 * APL];
  const int tid = threadIdx.x;
  const int b = blockIdx.y;
  const int p0 = blockIdx.x * 128;
  const int w = tid >> 6, l = tid & 63;
  const int wm = w >> 2, wn = w & 3;
  const int kb = l >> 4, il = l & 15;

  int abase[4];
#pragma unroll
  for (int mb = 0; mb < 4; ++mb)
    abase[mb] = ((wm * 4 + mb) * 16 + il) * 80 + kb * 16;
  int boff[4];
#pragma unroll
  for (int nbi = 0; nbi < 4; ++nbi)
    boff[nbi] = ((wn * 4 + nbi) * 16 + il) * 64 + kb * 16;

  f32x4 acc[4][4];
#pragma unroll
  for (int mb = 0; mb < 4; ++mb)
#pragma unroll
    for (int nbi = 0; nbi < 4; ++nbi) {
      f32x4 z = {0.f, 0.f, 0.f, 0.f};
      acc[mb][nbi] = z;
    }

  const char* WhB = (const char*)Wh;
  const char* WlB = (const char*)Wl;

  auto stageAB = [&](int c) {
    for (int s = tid; s < 128 * 8; s += 512) {
      int ciq = s & 7, px = s >> 3;
      int pg = p0 + px;
      u16 eh[4], el[4];
#pragma unroll
      for (int q = 0; q < 4; ++q) {
        int lc = c * 32 + ciq * 4 + q;
        float f = 0.f;
        if (lc < 4)
          f = t3[(size_t)b * 16384 + lc * 4096 + pg];
        else if (lc < 260)
          f = a[((size_t)b * 256 + (lc - 4)) * 4096 + pg];
        u16 h = f2bf(f);
        eh[q] = h;
        el[q] = f2bf(f - bf2f(h));
      }
      *(ushort4*)(lds_a + px * 80 + ciq * 8) = make_ushort4(eh[0], eh[1], eh[2], eh[3]);
      *(ushort4*)(lds_a + APL + px * 80 + ciq * 8) =
          make_ushort4(el[0], el[1], el[2], el[3]);
    }
  };

  for (int c = 0; c < 9; ++c) {
    __syncthreads();
    stageAB(c);
    __syncthreads();
    bf16x8 bh[4], bl[4];
#pragma unroll
    for (int nbi = 0; nbi < 4; ++nbi) {
      bh[nbi] = *(const bf16x8*)(WhB + (size_t)c * 16384 + boff[nbi]);
      bl[nbi] = *(const bf16x8*)(WlB + (size_t)c * 16384 + boff[nbi]);
    }
    bf16x8 avh[4], avl[4];
#pragma unroll
    for (int mb = 0; mb < 4; ++mb) {
      avh[mb] = *(const bf16x8*)(lds_a + abase[mb]);
      avl[mb] = *(const bf16x8*)(lds_a + APL + abase[mb]);
    }
#pragma unroll
    for (int mb = 0; mb < 4; ++mb)
#pragma unroll
      for (int nbi = 0; nbi < 4; ++nbi) {
        acc[mb][nbi] = __builtin_amdgcn_mfma_f32_16x16x32_bf16(
            avh[mb], bh[nbi], acc[mb][nbi], 0, 0, 0);
        acc[mb][nbi] = __builtin_amdgcn_mfma_f32_16x16x32_bf16(
            avh[mb], bl[nbi], acc[mb][nbi], 0, 0, 0);
        acc[mb][nbi] = __builtin_amdgcn_mfma_f32_16x16x32_bf16(
            avl[mb], bh[nbi], acc[mb][nbi], 0, 0, 0);
      }
  }

#pragma unroll
  for (int mb = 0; mb < 4; ++mb) {
    int pixb = p0 + (wm * 4 + mb) * 16 + kb * 4;
#pragma unroll
    for (int nbi = 0; nbi < 4; ++nbi) {
      int co = (wn * 4 + nbi) * 16 + il;
      float bv_ = bf[co];
      f32x4 v = acc[mb][nbi];
      float4 o = make_float4(v[0] + bv_, v[1] + bv_, v[2] + bv_, v[3] + bv_);
      *(float4*)(a + (size_t)(b * 256 + co) * 4096 + pixb) = o;
    }
  }
}

// ---------------------------------------------------------------- 9x9 s2 conv, MFMA fp16 2-pass, 16 waves
// (round-15 version, unchanged)
__global__ __launch_bounds__(1024) void conv9x9_mfma_k(const float* __restrict__ fused,
                                                       const u16* __restrict__ WTh,
                                                       const u16* __restrict__ WTl,
                                                       const float* __restrict__ bias,
                                                       float* __restrict__ praw) {
  constexpr int APLANE = 19 * 32 * 80;
  __shared__ __align__(16) char lds_a[2 * APLANE];
  const int tid = threadIdx.x;
  const int b = blockIdx.y, tile = blockIdx.x;
  const int p0 = tile * 128;
  const int oy0 = p0 / 28;
  const int w = tid >> 6, l = tid & 63;
  const int wm = w >> 3, wn = w & 7;
  const int kb = l >> 4, il = l & 15;

  int abase[4];
#pragma unroll
  for (int mb = 0; mb < 4; ++mb) {
    int p = p0 + (wm * 4 + mb) * 16 + il;
    int oy = p / 28, ox = p - oy * 28;
    abase[mb] = (2 * (oy - oy0)) * 2560 + ox * 80 + kb * 16;
  }
  int boff[2];
#pragma unroll
  for (int nbi = 0; nbi < 2; ++nbi)
    boff[nbi] = (wn * 32 + nbi * 16 + il) * 64 + kb * 16;

  f32x4 acc[4][2];
#pragma unroll
  for (int mb = 0; mb < 4; ++mb)
#pragma unroll
    for (int nbi = 0; nbi < 2; ++nbi) {
      f32x4 z = {0.f, 0.f, 0.f, 0.f};
      acc[mb][nbi] = z;
    }

  const float* Fb = fused + (size_t)b * 256 * 4096;
  const char* WhB = (const char*)WTh;
  const char* WlB = (const char*)WTl;

  auto stageA = [&](int g) {
    const float* src = Fb + (size_t)g * 32 * 4096;
    for (int s = tid; s < 19 * 63 * 8; s += 1024) {
      int ciq = s / 1197;
      int rem = s - ciq * 1197;
      int r = rem / 63, t63 = rem - r * 63;
      int x2 = (t63 < 32) ? 2 * t63 : 2 * (t63 - 32) + 1;
      int iy = 2 * oy0 + r;
      float a0 = 0.f, a1 = 0.f, a2 = 0.f, a3 = 0.f;
      if (iy < 64) {
        const float* pp0 = src + (size_t)(ciq * 4) * 4096 + iy * 64 + x2;
        a0 = pp0[0];
        a1 = pp0[4096];
        a2 = pp0[8192];
        a3 = pp0[12288];
      }
      u16 e0 = f2h(a0), e1 = f2h(a1), e2 = f2h(a2), e3 = f2h(a3);
      int off = (x2 & 1) * APLANE + (r * 32 + (x2 >> 1)) * 80 + ciq * 8;
      *(ushort4*)(lds_a + off) = make_ushort4(e0, e1, e2, e3);
    }
  };

  for (int g = 0; g < 8; ++g) {
    __syncthreads();
    stageA(g);
    __syncthreads();
#pragma unroll 3
    for (int t = 0; t < 81; ++t) {
      const char* pb = WhB + (size_t)(g * 81 + t) * 16384;
      const char* pl = WlB + (size_t)(g * 81 + t) * 16384;
      f16x8 bh[2], bl[2];
#pragma unroll
      for (int nbi = 0; nbi < 2; ++nbi) {
        bh[nbi] = *(const f16x8*)(pb + boff[nbi]);
        bl[nbi] = *(const f16x8*)(pl + boff[nbi]);
      }
      int ky = t / 9, kx = t - ky * 9;
      int toff = (kx & 1) * APLANE + ky * 2560 + (kx >> 1) * 80;
      f16x8 av[4];
#pragma unroll
      for (int mb = 0; mb < 4; ++mb)
        av[mb] = *(const f16x8*)(lds_a + abase[mb] + toff);
#pragma unroll
      for (int mb = 0; mb < 4; ++mb)
#pragma unroll
        for (int nbi = 0; nbi < 2; ++nbi) {
          acc[mb][nbi] = __builtin_amdgcn_mfma_f32_16x16x32_f16(
              av[mb], bh[nbi], acc[mb][nbi], 0, 0, 0);
          acc[mb][nbi] = __builtin_amdgcn_mfma_f32_16x16x32_f16(
              av[mb], bl[nbi], acc[mb][nbi], 0, 0, 0);
        }
    }
  }

#pragma unroll
  for (int mb = 0; mb < 4; ++mb) {
    int pixb = p0 + (wm * 4 + mb) * 16 + kb * 4;
    if (pixb < 784) {
#pragma unroll
      for (int nbi = 0; nbi < 2; ++nbi) {
        int co = wn * 32 + nbi * 16 + il;
        float bv_ = bias[co];
        f32x4 v = acc[mb][nbi];
        float4 o = make_float4(v[0] + bv_, v[1] + bv_, v[2] + bv_, v[3] + bv_);
        *(float4*)(praw + (size_t)(b * 256 + co) * 784 + pixb) = o;
      }
    }
  }
}

// ---------------------------------------------------------------- capsule squash: p(B,256,784) -> u(B,25088,8)
__global__ __launch_bounds__(256) void squash_caps_k(const float* __restrict__ p,
                                                     float* __restrict__ u) {
  int idx = blockIdx.x * 256 + threadIdx.x;
  if (idx >= BSZ * 25088) return;
  int b = idx / 25088;
  int cap = idx - b * 25088;
  int prim = cap / 784, pix = cap - prim * 784;
  const float* pp = p + ((size_t)b * 256 + prim * 8) * 784 + pix;
  float x[8];
  float sn = 0.f;
#pragma unroll
  for (int d = 0; d < 8; ++d) {
    x[d] = pp[(size_t)d * 784];
    sn += x[d] * x[d];
  }
  float scale = sn / ((1.f + sn) * sqrtf(sn + 1e-8f));
  float4 r0 = {x[0] * scale, x[1] * scale, x[2] * scale, x[3] * scale};
  float4 r1 = {x[4] * scale, x[5] * scale, x[6] * scale, x[7] * scale};
  float4* dst = (float4*)(u + (size_t)idx * 8);
  dst[0] = r0;
  dst[1] = r1;
}

// ---------------------------------------------------------------- u_hat = einsum('iodk,bik->biod')
__global__ __launch_bounds__(256) void uhat_k(const float* __restrict__ u,
                                              const float* __restrict__ w_r,
                                              float* __restrict__ u_hat) {
  int i = blockIdx.x * 256 + threadIdx.x;  // 25088
  int b = blockIdx.y;
  const float4* up = (const float4*)(u + ((size_t)b * 25088 + i) * 8);
  float4 ua = up[0], ub = up[1];
  const float4* wr = (const float4*)(w_r + (size_t)i * 256);
  float res[32];
#pragma unroll
  for (int od = 0; od < 32; ++od) {
    float4 wa = wr[od * 2], wb = wr[od * 2 + 1];
    res[od] = wa.x * ua.x + wa.y * ua.y + wa.z * ua.z + wa.w * ua.w +
              wb.x * ub.x + wb.y * ub.y + wb.z * ub.z + wb.w * ub.w;
  }
  float4* dst = (float4*)(u_hat + ((size_t)b * 25088 + i) * 32);
#pragma unroll
  for (int q = 0; q < 8; ++q)
    dst[q] = make_float4(res[4 * q], res[4 * q + 1], res[4 * q + 2], res[4 * q + 3]);
}

// ---------------------------------------------------------------- routing iter0: s_j partials (c = 0.5)
__global__ __launch_bounds__(256) void route_sj_k(const float* __restrict__ u_hat,
                                                  float* __restrict__ sj_part) {
  int b = blockIdx.x;
  int seg = blockIdx.y;
  int t = threadIdx.x;
  float acc[32];
#pragma unroll
  for (int j = 0; j < 32; ++j) acc[j] = 0.f;
  int i0 = seg * 3136;
  for (int i = i0 + t; i < i0 + 3136; i += 256) {
    const float4* uh = (const float4*)(u_hat + ((size_t)b * 25088 + i) * 32);
#pragma unroll
    for (int q = 0; q < 4; ++q) {
      float4 va = uh[q];
      acc[4 * q + 0] += 0.5f * va.x;
      acc[4 * q + 1] += 0.5f * va.y;
      acc[4 * q + 2] += 0.5f * va.z;
      acc[4 * q + 3] += 0.5f * va.w;
      float4 vb = uh[4 + q];
      acc[16 + 4 * q + 0] += 0.5f * vb.x;
      acc[16 + 4 * q + 1] += 0.5f * vb.y;
      acc[16 + 4 * q + 2] += 0.5f * vb.z;
      acc[16 + 4 * q + 3] += 0.5f * vb.w;
    }
  }
#pragma unroll
  for (int j = 0; j < 32; ++j) {
    acc[j] += __shfl_down(acc[j], 32);
    acc[j] += __shfl_down(acc[j], 16);
    acc[j] += __shfl_down(acc[j], 8);
    acc[j] += __shfl_down(acc[j], 4);
    acc[j] += __shfl_down(acc[j], 2);
    acc[j] += __shfl_down(acc[j], 1);
  }
  __shared__ float red[4][32];
  int wave = t >> 6, lane = t & 63;
  if (lane == 0) {
#pragma unroll
    for (int j = 0; j < 32; ++j) red[wave][j] = acc[j];
  }
  __syncthreads();
  if (t < 32) {
    float s = red[0][t] + red[1][t] + red[2][t] + red[3][t];
    sj_part[((size_t)b * 8 + seg) * 32 + t] = s;
  }
}

// ---------------------------------------------------------------- routing fused upd+sj (iters 1,2)
// e = u_hat . v ; b = first ? e : b_ij + e (b_ij written when first);
// c = softmax(b) ; accumulate s_j partials. One u_hat read per iteration.
__global__ __launch_bounds__(256) void route_fsj_k(const float* __restrict__ u_hat,
                                                   const float* __restrict__ v,
                                                   float* __restrict__ b_ij,
                                                   float* __restrict__ sj_part, int first) {
  int b = blockIdx.x;
  int seg = blockIdx.y;
  int t = threadIdx.x;
  float4 vp[8];
  const float4* vv = (const float4*)(v + b * 32);
#pragma unroll
  for (int q = 0; q < 8; ++q) vp[q] = vv[q];
  float acc[32];
#pragma unroll
  for (int j = 0; j < 32; ++j) acc[j] = 0.f;
  int i0 = seg * 3136;
  for (int i = i0 + t; i < i0 + 3136; i += 256) {
    const float4* uhp = (const float4*)(u_hat + ((size_t)b * 25088 + i) * 32);
    float4 uh[8];
#pragma unroll
    for (int q = 0; q < 8; ++q) uh[q] = uhp[q];
    float e0 = 0.f, e1 = 0.f;
#pragma unroll
    for (int q = 0; q < 4; ++q) {
      e0 += uh[q].x * vp[q].x + uh[q].y * vp[q].y + uh[q].z * vp[q].z + uh[q].w * vp[q].w;
      e1 += uh[4 + q].x * vp[4 + q].x + uh[4 + q].y * vp[4 + q].y +
            uh[4 + q].z * vp[4 + q].z + uh[4 + q].w * vp[4 + q].w;
    }
    size_t o = ((size_t)b * 25088 + i) * 2;
    float b0, b1;
    if (first) {
      b0 = e0;
      b1 = e1;
      b_ij[o + 0] = e0;
      b_ij[o + 1] = e1;
    } else {
      b0 = b_ij[o + 0] + e0;
      b1 = b_ij[o + 1] + e1;
    }
    float m = fmaxf(b0, b1);
    float x0 = expf(b0 - m), x1 = expf(b1 - m);
    float inv = 1.f / (x0 + x1);
    float c0 = x0 * inv, c1 = x1 * inv;
#pragma unroll
    for (int q = 0; q < 4; ++q) {
      acc[4 * q + 0] += c0 * uh[q].x;
      acc[4 * q + 1] += c0 * uh[q].y;
      acc[4 * q + 2] += c0 * uh[q].z;
      acc[4 * q + 3] += c0 * uh[q].w;
      acc[16 + 4 * q + 0] += c1 * uh[4 + q].x;
      acc[16 + 4 * q + 1] += c1 * uh[4 + q].y;
      acc[16 + 4 * q + 2] += c1 * uh[4 + q].z;
      acc[16 + 4 * q + 3] += c1 * uh[4 + q].w;
    }
  }
#pragma unroll
  for (int j = 0; j < 32; ++j) {
    acc[j] += __shfl_down(acc[j], 32);
    acc[j] += __shfl_down(acc[j], 16);
    acc[j] += __shfl_down(acc[j], 8);
    acc[j] += __shfl_down(acc[j], 4);
    acc[j] += __shfl_down(acc[j], 2);
    acc[j] += __shfl_down(acc[j], 1);
  }
  __shared__ float red[4][32];
  int wave = t >> 6, lane = t & 63;
  if (lane == 0) {
#pragma unroll
    for (int j = 0; j < 32; ++j) red[wave][j] = acc[j];
  }
  __syncthreads();
  if (t < 32) {
    float s = red[0][t] + red[1][t] + red[2][t] + red[3][t];
    sj_part[((size_t)b * 8 + seg) * 32 + t] = s;
  }
}

// ---------------------------------------------------------------- routing: finalize v
__global__ __launch_bounds__(256) void route_fin_k(const float* __restrict__ sj_part,
                                                   float* __restrict__ v,
                                                   float* __restrict__ out, int final_it) {
  int idx = blockIdx.x * 256 + threadIdx.x;
  if (idx >= BSZ * 32) return;
  int b = idx >> 5, j = idx & 31;
  float s = 0.f;
#pragma unroll
  for (int seg = 0; seg < 8; ++seg) s += sj_part[((size_t)b * 8 + seg) * 32 + j];
  float sn = s * s;
  float vv = sn * s / ((1.f + sn) * sqrtf(sn + 1e-8f));
  v[idx] = vv;
  if (final_it) out[idx] = fabsf(vv);
}

// ================================================================ launch
extern "C" void kernel_launch(void* const* d_in, const int* in_sizes, int n_in,
                              void* d_out, int out_size, void* d_ws, size_t ws_size,
                              hipStream_t stream) {
  (void)in_sizes; (void)n_in; (void)out_size;
  const float* x    = (const float*)d_in[0];
  const float* w_t1 = (const float*)d_in[1];
  const float* b_t1 = (const float*)d_in[2];
  const float* w_t2 = (const float*)d_in[3];
  const float* b_t2 = (const float*)d_in[4];
  const float* w_t3 = (const float*)d_in[5];
  const float* b_t3 = (const float*)d_in[6];
  const float* w_s1 = (const float*)d_in[7];
  const float* b_s1 = (const float*)d_in[8];
  const float* w_s2 = (const float*)d_in[9];
  const float* b_s2 = (const float*)d_in[10];
  const float* w_s3 = (const float*)d_in[11];
  const float* b_s3 = (const float*)d_in[12];
  const float* w_f  = (const float*)d_in[13];
  const float* b_f  = (const float*)d_in[14];
  const float* w_p  = (const float*)d_in[15];
  const float* b_p  = (const float*)d_in[16];
  const float* w_r  = (const float*)d_in[17];
  float* out = (float*)d_out;

  char* ws = (char*)d_ws;
  if (ws_size < 238854144ull) return;
  // region 0: fused / uhat
  float* fused = (float*)(ws + 0);
  float* uhat  = (float*)(ws + 0);
  // region 1 (134,217,728): s2q -> praw/u/b_ij
  float* s2q   = (float*)(ws + 134217728);
  float* praw  = (float*)(ws + 134217728);
  float* u     = (float*)(ws + 159907840);
  float* b_ij  = (float*)(ws + 185597952);
  // region 2 (201,326,592): s1 -> t1/t2/t3/wTh/wTl
  float* s1    = (float*)(ws + 201326592);
  float* t1    = (float*)(ws + 201326592);
  float* t2    = (float*)(ws + 201850880);
  float* t3    = (float*)(ws + 202899456);
  u16*   wTh   = (u16*)  (ws + 204996608);
  u16*   wTl   = (u16*)  (ws + 215613440);
  // tail (234,881,024): persistent small tables
  u16*   w3a_h = (u16*)  (ws + 234881024);
  u16*   w3a_l = (u16*)  (ws + 235028480);
  u16*   w3b_h = (u16*)  (ws + 235175936);
  u16*   w3b_l = (u16*)  (ws + 235765760);
  u16*   wf1_h = (u16*)  (ws + 236355584);
  u16*   wf1_l = (u16*)  (ws + 236503040);
  float* sjp   = (float*)(ws + 236650496);
  float* vbuf  = (float*)(ws + 236683264);

  // small weight tables (tail region -- never clobbered)
  transpose_w3_k<128, 2><<<18, 256, 0, stream>>>(w_s2, w3a_h, w3a_l);
  transpose_w3_k<256, 4><<<36, 256, 0, stream>>>(w_s3, w3b_h, w3b_l);
  transpose_wf1_k<<<9, 256, 0, stream>>>(w_f, wf1_h, wf1_l);

  // spectral: s1 scalar conv, then s2 MFMA conv (consumes s1)
  conv3x3_relu_k<1, 1><<<dim3(16, 4, BSZ), 256, 0, stream>>>(x, w_s1, b_s1, s1, 64);
  conv3x3_mfma_k<4, 2, 2, 128><<<dim3(16, BSZ), 512, 0, stream>>>(s1, w3a_h, w3a_l, b_s2, s2q);

  // s1 now dead: temporal branch + 9x9 weight tables move into its region
  conv1d_relu_k<<<512, 256, 0, stream>>>(x, w_t1, b_t1, t1, 64, 64);
  conv1d_relu_k<<<1024, 256, 0, stream>>>(t1, w_t2, b_t2, t2, 64, 128);
  conv1d_relu_k<<<2048, 256, 0, stream>>>(t2, w_t3, b_t3, t3, 128, 256);
  transpose_wp_k<<<648, 256, 0, stream>>>(w_p, wTh, wTl);

  // s3 MFMA conv -> fused
  conv3x3_mfma_k<2, 4, 4, 256><<<dim3(32, BSZ), 512, 0, stream>>>(s2q, w3b_h, w3b_l, b_s3, fused);

  // fusion via MFMA, in-place on fused (exact bf16 hi/lo)
  fuse_mfma_k<<<dim3(32, BSZ), 512, 0, stream>>>(t3, wf1_h, wf1_l, b_f, fused);

  // primary capsules via MFMA fp16 2-pass, 16 waves (praw over dead s2q)
  conv9x9_mfma_k<<<dim3(7, BSZ), 1024, 0, stream>>>(fused, wTh, wTl, b_p, praw);
  squash_caps_k<<<3136, 256, 0, stream>>>(praw, u);

  // u_hat (overwrites fused region)
  uhat_k<<<dim3(98, BSZ), 256, 0, stream>>>(u, w_r, uhat);

  // dynamic routing, 3 iterations (upd fused into sj for iters 1,2)
  route_sj_k<<<dim3(BSZ, 8), 256, 0, stream>>>(uhat, sjp);
  route_fin_k<<<4, 256, 0, stream>>>(sjp, vbuf, out, 0);
  route_fsj_k<<<dim3(BSZ, 8), 256, 0, stream>>>(uhat, vbuf, b_ij, sjp, 1);
  route_fin_k<<<4, 256, 0, stream>>>(sjp, vbuf, out, 0);
  route_fsj_k<<<dim3(BSZ, 8), 256, 0, stream>>>(uhat, vbuf, b_ij, sjp, 0);
  route_fin_k<<<4, 256, 0, stream>>>(sjp, vbuf, out, 1);
}